// Round 28
// baseline (130.957 us; speedup 1.0000x reference)
//
#include <hip/hip_runtime.h>
#include <stdint.h>
#include <stddef.h>

// Problem constants
#define B_  16
#define C_  512
#define N_  1024    // H*W = 32*32
#define NH  8
#define HD  64

typedef __attribute__((ext_vector_type(8))) short bf16x8;
typedef __attribute__((ext_vector_type(4))) float f32x4;
typedef __attribute__((ext_vector_type(2))) __bf16 bf16x2t;
typedef __attribute__((ext_vector_type(2))) unsigned uint2v;

__device__ __forceinline__ float bf2f(short s) {
    unsigned u = ((unsigned)(unsigned short)s) << 16;
    return __builtin_bit_cast(float, u);
}
// Compiler-visible f32->bf16 (RNE): lowers to v_cvt_pk_bf16_f32 on gfx950.
__device__ __forceinline__ unsigned packcvt(float lo, float hi) {
    bf16x2t v = { (__bf16)lo, (__bf16)hi };
    return __builtin_bit_cast(unsigned, v);
}
__device__ __forceinline__ short f2bf_hw(float f) {
    __bf16 b = (__bf16)f;
    return __builtin_bit_cast(short, b);
}
// Native 2^x (v_exp_f32 IS exp2; denorm flush-to-zero is fine for softmax tails)
__device__ __forceinline__ float fexp2(float x) {
#if __has_builtin(__builtin_amdgcn_exp2f)
    return __builtin_amdgcn_exp2f(x);
#else
    return exp2f(x);
#endif
}
// Two-register half-swaps (gfx950). swap32: a's lanes32-63 <-> b's lanes0-31.
// swap16: a's odd 16-rows <-> b's even 16-rows.
__device__ __forceinline__ void plswap32(unsigned& a, unsigned& b) {
#if __has_builtin(__builtin_amdgcn_permlane32_swap)
    uint2v r = __builtin_amdgcn_permlane32_swap(a, b, false, false);
    a = r.x; b = r.y;
#else
    unsigned ax = (unsigned)__shfl_xor((int)a, 32, 64), bx = (unsigned)__shfl_xor((int)b, 32, 64);
    bool hi = (threadIdx.x & 32) != 0;
    unsigned na = hi ? bx : a, nb = hi ? b : ax;
    a = na; b = nb;
#endif
}
__device__ __forceinline__ void plswap16(unsigned& a, unsigned& b) {
#if __has_builtin(__builtin_amdgcn_permlane16_swap)
    uint2v r = __builtin_amdgcn_permlane16_swap(a, b, false, false);
    a = r.x; b = r.y;
#else
    unsigned ax = (unsigned)__shfl_xor((int)a, 16, 64), bx = (unsigned)__shfl_xor((int)b, 16, 64);
    bool hi = (threadIdx.x & 16) != 0;
    unsigned na = hi ? bx : a, nb = hi ? b : ax;
    a = na; b = nb;
#endif
}
__device__ __forceinline__ float bcf(unsigned u) { return __builtin_bit_cast(float, u); }
__device__ __forceinline__ unsigned bcu(float f) { return __builtin_bit_cast(unsigned, f); }
// butterfly reduce across lane bits 4,5 (the 4 lane-groups): result valid in all lanes
__device__ __forceinline__ float redsum_lg(float x) {
    unsigned a = bcu(x), b = a; plswap32(a, b);
    float s = bcf(a) + bcf(b);
    a = bcu(s); b = a; plswap16(a, b);
    return bcf(a) + bcf(b);
}

#define MFMA16(a, b, c) __builtin_amdgcn_mfma_f32_16x16x32_bf16((a), (b), (c), 0, 0, 0)

typedef __attribute__((address_space(3))) unsigned int lds_u32;
typedef __attribute__((address_space(1))) unsigned int glb_u32;
// dest = wave-uniform LDS base + lane*16 (m104); global src is per-lane.
__device__ __forceinline__ void gload16(const void* g, void* l) {
    __builtin_amdgcn_global_load_lds((const glb_u32*)g, (lds_u32*)l, 16, 0, 0);
}

// ---------------------------------------------------------------- prep + mlp1 (merged, R27 config)
__global__ __launch_bounds__(256) void k_prep1(
        const float* __restrict__ qkv_w, const float* __restrict__ out_w,
        short* __restrict__ qkvwT, short* __restrict__ outwT,
        float4* __restrict__ ropetab,
        const float* __restrict__ temb, const float* __restrict__ w1,
        const float* __restrict__ b1, float* __restrict__ h) {
    int bid = blockIdx.x, tid = threadIdx.x;
    __shared__ float ts[64][65];
    __shared__ float ps[8][32];
    if (bid < 256) {
        const float* src; short* dst; int J, jt, kt;
        if (bid < 192) { src = qkv_w; dst = qkvwT; J = 1536; jt = (bid % 24) * 64; kt = (bid / 24) * 64; }
        else { int b2 = bid - 192; src = out_w; dst = outwT; J = 512; jt = (b2 & 7) * 64; kt = (b2 >> 3) * 64; }
        int r = tid >> 4, c4 = (tid & 15) * 4;
        for (int rr = 0; rr < 64; rr += 16) {
            float4 v = *(const float4*)(src + (size_t)(kt + rr + r) * J + jt + c4);
            ts[c4 + 0][rr + r] = v.x;
            ts[c4 + 1][rr + r] = v.y;
            ts[c4 + 2][rr + r] = v.z;
            ts[c4 + 3][rr + r] = v.w;
        }
        __syncthreads();
        int jr = tid >> 2, kc = (tid & 3) * 16;
        unsigned w[8];
#pragma unroll
        for (int i = 0; i < 8; i++) w[i] = packcvt(ts[jr][kc + 2 * i], ts[jr][kc + 2 * i + 1]);
        short* dp = dst + (size_t)(jt + jr) * 512 + kt + kc;
        *(uint4*)(dp)     = make_uint4(w[0], w[1], w[2], w[3]);
        *(uint4*)(dp + 8) = make_uint4(w[4], w[5], w[6], w[7]);
    } else if (bid < 384) {
        int idx = (bid - 256) * 256 + tid;       // 32768 entries
        int n = idx >> 5, dq = idx & 31, i = dq & 15;
        float w = powf(100.0f, -(float)i * (1.0f / 16.0f));
        float y = (float)(n >> 5), xx = (float)(n & 31);
        ropetab[idx] = make_float4(cosf(y * w), sinf(y * w), cosf(xx * w), sinf(xx * w));
    } else {
        // mlp1: rem = bid-384; jt = rem%16, b = rem/16
        int rem = bid - 384;
        int jt = rem & 15, b = rem >> 4;
        int jl = tid & 31, j = jt * 32 + jl, ks = tid >> 5;
        float* tl = &ts[0][0];                    // reuse LDS (512 floats)
        tl[tid] = temb[b * 512 + tid];
        tl[tid + 256] = temb[b * 512 + tid + 256];
        __syncthreads();
        float acc = 0.f;
        const float* wp = w1 + (size_t)(ks * 64) * 512 + j;
#pragma unroll 8
        for (int kk = 0; kk < 64; kk++) acc += tl[ks * 64 + kk] * wp[(size_t)kk * 512];
        ps[ks][jl] = acc;
        __syncthreads();
        if (tid < 32) {
            float s = ((ps[0][tid] + ps[1][tid]) + (ps[2][tid] + ps[3][tid]))
                    + ((ps[4][tid] + ps[5][tid]) + (ps[6][tid] + ps[7][tid]));
            s += b1[jt * 32 + tid];
            h[b * 512 + jt * 32 + tid] = s / (1.0f + __expf(-s));
        }
    }
}

__global__ __launch_bounds__(256) void k_mlp2(
        const float* __restrict__ h, const float* __restrict__ w2, const float* __restrict__ b2,
        float* __restrict__ gbout) {
    int b = blockIdx.y, jt = blockIdx.x, tid = threadIdx.x;
    int jl = tid & 31, j = jt * 32 + jl, ks = tid >> 5;
    __shared__ float hl[512];
    __shared__ float ps[8][32];
    hl[tid] = h[b * 512 + tid];
    hl[tid + 256] = h[b * 512 + tid + 256];
    __syncthreads();
    float acc = 0.f;
    const float* wp = w2 + (size_t)(ks * 64) * 1024 + j;
#pragma unroll 8
    for (int kk = 0; kk < 64; kk++) acc += hl[ks * 64 + kk] * wp[(size_t)kk * 1024];
    ps[ks][jl] = acc;
    __syncthreads();
    if (tid < 32) {
        float s = ((ps[0][tid] + ps[1][tid]) + (ps[2][tid] + ps[3][tid]))
                + ((ps[4][tid] + ps[5][tid]) + (ps[6][tid] + ps[7][tid]));
        gbout[b * 1024 + jt * 32 + tid] = s + b2[jt * 32 + tid];
    }
}

// ---------------------------------------------------------------- AdaCLN -> tokens bf16 (B,N,C)
// 32-pixel tiles, grid (32,16) = 512 blocks = 2 blocks/CU (was 256 = 1/CU;
// latency-bound kernel -> double TLP cover). Pass 1: q=tid&7 (8 quads = 32
// px), s=tid>>3 (32 slices x 16 ch); reduction: tid<32 owns pixel tid.
// Bank audit: rs4 store linear; xs write (cl+4q)%32 <=2-way; xs read
// (8ch+p)%32 exactly 2-way -> all free (m136).
__global__ __launch_bounds__(256) void k_adacln(
        const float* __restrict__ x, const float* __restrict__ gb, short* __restrict__ tokens) {
    int b = blockIdx.y, n0 = blockIdx.x * 32;
    int tid = threadIdx.x;
    const float* xb = x + (size_t)b * C_ * N_;
    __shared__ float4 rs4[32][8], rq4[32][8];
    __shared__ float mean_s[32], rstd_s[32];
    __shared__ float xs[64][33];

    // pass 1: stats
    {
        int q = tid & 7, s = tid >> 3;
        float4 sum = make_float4(0.f, 0.f, 0.f, 0.f);
        float4 sq  = make_float4(0.f, 0.f, 0.f, 0.f);
        const float* xp = xb + (size_t)(s * 16) * N_ + n0 + q * 4;
#pragma unroll 8
        for (int ci = 0; ci < 16; ci++) {
            float4 v = *(const float4*)(xp + (size_t)ci * N_);
            sum.x += v.x; sum.y += v.y; sum.z += v.z; sum.w += v.w;
            sq.x += v.x * v.x; sq.y += v.y * v.y; sq.z += v.z * v.z; sq.w += v.w * v.w;
        }
        rs4[s][q] = sum; rq4[s][q] = sq;
    }
    __syncthreads();
    if (tid < 32) {
        int q = tid >> 2, j = tid & 3;
        float s1 = 0.f, s2 = 0.f;
#pragma unroll
        for (int s = 0; s < 32; s++) {
            float4 a = rs4[s][q], c = rq4[s][q];
            s1 += (&a.x)[j];
            s2 += (&c.x)[j];
        }
        float mu = s1 * (1.0f / 512.0f);
        float var = s2 * (1.0f / 512.0f) - mu * mu;
        mean_s[tid] = mu;                         // pixel index = tid
        rstd_s[tid] = rsqrtf(var + 1e-6f);
    }
    const float* gam = gb + b * 1024;
    const float* bet = gam + 512;
    int ch = tid & 7;
    for (int ct = 0; ct < 8; ct++) {
        __syncthreads();
        // stage 64 channels x 32 pixels, float4 over pixels
#pragma unroll
        for (int itr = 0; itr < 2; itr++) {
            int cl = itr * 32 + (tid >> 3), q = tid & 7;
            float4 v = *(const float4*)(xb + (size_t)(ct * 64 + cl) * N_ + n0 + q * 4);
            xs[cl][q * 4 + 0] = v.x;
            xs[cl][q * 4 + 1] = v.y;
            xs[cl][q * 4 + 2] = v.z;
            xs[cl][q * 4 + 3] = v.w;
        }
        __syncthreads();
        {
            int p = tid >> 3;                     // 0..31
            float mu = mean_s[p], rt = rstd_s[p];
            float v[8];
#pragma unroll
            for (int j = 0; j < 8; j++) {
                int c = ct * 64 + ch * 8 + j;
                v[j] = (xs[ch * 8 + j][p] - mu) * rt * (1.0f + gam[c]) + bet[c];
            }
            uint4 ov = make_uint4(packcvt(v[0], v[1]), packcvt(v[2], v[3]),
                                  packcvt(v[4], v[5]), packcvt(v[6], v[7]));
            *(uint4*)(tokens + ((size_t)(b * N_ + n0 + p)) * C_ + ct * 64 + ch * 8) = ov;
        }
    }
}

// ---------------------------------------------------------------- QKV GEMM + fused RoPE
// BK=64 (R21/R22-measured win for this kernel: 1536 blocks -> ~5-6/CU TLP).
__global__ __launch_bounds__(256) void k_gemm_qkv(
        const short* __restrict__ A, const short* __restrict__ Bt,
        const float4* __restrict__ ropetab,
        short* __restrict__ qr, short* __restrict__ kr, short* __restrict__ vt) {
    __shared__ short Asm[128 * 64];
    __shared__ short Bsm[128 * 64];
    int wgid = blockIdx.x;
    int orig = (wgid & 7) * 192 + (wgid >> 3);   // bijective: 1536 = 8*192
    int bx = orig % 12, by = orig / 12;
    int tid = threadIdx.x, wv = tid >> 6, ln = tid & 63;
    int wr = wv >> 1, wc = wv & 1, lr = ln & 15, lg = ln >> 4;
    const short* Ab = A + (size_t)by * 128 * 512;
    const short* Bb = Bt + (size_t)bx * 128 * 512;
    f32x4 acc[4][4] = {};
    int lrow = ln >> 3, lch = ln & 7;
    int schx = (lch ^ (lrow & 7)) * 8;           // swizzled source col (shorts)
    for (int kt = 0; kt < 8; kt++) {
        int kb = kt * 64;
#pragma unroll
        for (int g = 0; g < 4; g++) {
            int row = wv * 32 + g * 8 + lrow;
            gload16(Ab + (size_t)row * 512 + kb + schx, (void*)(Asm + (wv * 32 + g * 8) * 64));
            gload16(Bb + (size_t)row * 512 + kb + schx, (void*)(Bsm + (wv * 32 + g * 8) * 64));
        }
        __syncthreads();
        bf16x8 af[2][4], bfr[2][4];
#pragma unroll
        for (int kk = 0; kk < 2; kk++) {
#pragma unroll
            for (int m = 0; m < 4; m++) {
                int R = wr * 64 + m * 16 + lr;
                af[kk][m] = *(const bf16x8*)(Asm + R * 64 + ((lg + kk * 4) ^ (R & 7)) * 8);
            }
#pragma unroll
            for (int f = 0; f < 4; f++) {
                int R = wc * 64 + f * 16 + lr;
                bfr[kk][f] = *(const bf16x8*)(Bsm + R * 64 + ((lg + kk * 4) ^ (R & 7)) * 8);
            }
        }
#pragma unroll
        for (int kk = 0; kk < 2; kk++)
#pragma unroll
            for (int m = 0; m < 4; m++)
#pragma unroll
                for (int f = 0; f < 4; f++)
                    acc[m][f] = MFMA16(af[kk][m], bfr[kk][f], acc[m][f]);
        __syncthreads();
    }
    int mbase = by * 128;
    int sec = bx >> 2;
    int h = (2 * bx + wc) & 7;
    if (sec < 2) {
        short* dst0 = (sec == 0) ? qr : kr;
#pragma unroll
        for (int m = 0; m < 4; m++) {
            int gmb = mbase + wr * 64 + m * 16 + lg * 4;
#pragma unroll
            for (int r = 0; r < 4; r++) {
                int gm = gmb + r; int b = gm >> 10, n = gm & 1023;
                short* rowp = dst0 + (((size_t)b * NH + h) * N_ + n) * HD;
                const float4* tr = ropetab + n * 32;
#pragma unroll
                for (int f2 = 0; f2 < 2; f2++) {
                    int d_lo = f2 * 16 + lr;
                    float4 t = tr[d_lo];
                    float a = acc[m][f2][r], bb2 = acc[m][f2 + 2][r];
                    rowp[d_lo]      = f2bf_hw(a * t.x - bb2 * t.y);
                    rowp[d_lo + 32] = f2bf_hw(bb2 * t.z + a * t.w);
                }
            }
        }
    } else {
#pragma unroll
        for (int m = 0; m < 4; m++) {
            int gmb = mbase + wr * 64 + m * 16 + lg * 4;
            int b = gmb >> 10, n0 = gmb & 1023;
#pragma unroll
            for (int f = 0; f < 4; f++) {
                int d = f * 16 + lr;
                uint2 val;
                val.x = packcvt(acc[m][f][0], acc[m][f][1]);
                val.y = packcvt(acc[m][f][2], acc[m][f][3]);
                *(uint2*)(vt + (((size_t)b * NH + h) * HD + d) * N_ + n0) = val;
            }
        }
    }
}

// ---------------------------------------------------------------- flash attention v12 (R25 config, depth 4)
__global__ __launch_bounds__(512) void k_flash12(
        const short* __restrict__ qr, const short* __restrict__ kr, const short* __restrict__ vt,
        short* __restrict__ attn_out) {
    __shared__ short Ks[4][4096];        // [k=64][d=64] chunk-swizzled
    __shared__ short Vs[4][4096];        // [d=64][k=64] chunk-swizzled
    int bh = blockIdx.x, b = bh >> 3, h = bh & 7;
    int qt = blockIdx.y;
    int tid = threadIdx.x, wv = tid >> 6, ln = tid & 63;
    int lr = ln & 15, lg = ln >> 4;
    int qhalf = wv >> 2, w4 = wv & 3;
    const short* Qb = qr + ((size_t)bh * N_ + qt * 256 + qhalf * 128 + w4 * 32) * HD;
    const short* Kb = kr + (size_t)bh * N_ * HD;
    const short* Vb = vt + (size_t)bh * HD * N_;

    // Q as B-operand fragments, pre-scaled by 0.125*log2(e): S lands in log2 domain
    const float QSCALE = 0.125f * 1.44269504f;
    bf16x8 qf[2][2];
#pragma unroll
    for (int qg = 0; qg < 2; qg++)
#pragma unroll
        for (int hf = 0; hf < 2; hf++) {
            bf16x8 raw = *(const bf16x8*)(Qb + (qg * 16 + lr) * 64 + hf * 32 + lg * 8);
            bf16x8 sc;
#pragma unroll
            for (int j = 0; j < 8; j++) sc[j] = f2bf_hw(bf2f(raw[j]) * QSCALE);
            qf[qg][hf] = sc;
        }

    int srow = ln >> 3, cpos = ln & 7;
    int rloc = wv * 8 + srow;            // 0..63: this wave's K-row / V-row
    int csrc = cpos ^ (srow & 7);

    float l_part[2] = {0.f, 0.f};
    f32x4 ao[2][4] = {};

    // drain Q vector-loads so vmcnt counts only staging gloads from here on
    asm volatile("s_waitcnt vmcnt(0)" ::: "memory");
    __builtin_amdgcn_sched_barrier(0);

    // stage tiles 0,1,2 (2 gloads/wave each)
#pragma unroll
    for (int t0 = 0; t0 < 3; t0++) {
        gload16(Kb + ((size_t)(t0 * 64 + rloc)) * 64 + csrc * 8,
                (void*)&Ks[t0][rloc * 64]);
        gload16(Vb + ((size_t)rloc) * 1024 + t0 * 64 + csrc * 8,
                (void*)&Vs[t0][rloc * 64]);
    }
    asm volatile("s_waitcnt vmcnt(4)" ::: "memory");   // tile 0 complete
    __builtin_amdgcn_s_barrier();
    __builtin_amdgcn_sched_barrier(0);

    for (int kt = 0; kt < 16; kt++) {
        int cur = kt & 3;
        if (kt < 13) {
            int nxt = (kt + 3) & 3, ktn = kt + 3;
            gload16(Kb + ((size_t)(ktn * 64 + rloc)) * 64 + csrc * 8,
                    (void*)&Ks[nxt][rloc * 64]);
            gload16(Vb + ((size_t)rloc) * 1024 + ktn * 64 + csrc * 8,
                    (void*)&Vs[nxt][rloc * 64]);
        }

        // QK^T (swapped): sT[qg][f][r] = S^T[k = f*16+lg*4+r][q = qg*16+lr] (log2 domain)
        f32x4 sT[2][4];
        __builtin_amdgcn_s_setprio(1);
#pragma unroll
        for (int f = 0; f < 4; f++) {
            int r = f * 16 + lr;
            const short* kp = &Ks[cur][r * 64];
            bf16x8 ka  = *(const bf16x8*)(kp + ((lg ^ (r & 7)) * 8));
            bf16x8 kb2 = *(const bf16x8*)(kp + (((4 + lg) ^ (r & 7)) * 8));
#pragma unroll
            for (int qg = 0; qg < 2; qg++) {
                f32x4 s = {};
                s = MFMA16(ka, qf[qg][0], s);
                s = MFMA16(kb2, qf[qg][1], s);
                sT[qg][f] = s;
            }
        }
        __builtin_amdgcn_s_setprio(0);

        // fixed-shift softmax: p = exp2(s) directly; l accumulated per-lane
        union U4 { unsigned u[4]; bf16x8 v; };
        U4 pb[2][2];
#pragma unroll
        for (int qg = 0; qg < 2; qg++) {
            float rsum = 0.f;
            unsigned pk[4][2];
#pragma unroll
            for (int f = 0; f < 4; f++) {
                float p0 = fexp2(sT[qg][f][0]);
                float p1 = fexp2(sT[qg][f][1]);
                float p2 = fexp2(sT[qg][f][2]);
                float p3 = fexp2(sT[qg][f][3]);
                rsum += (p0 + p1) + (p2 + p3);
                pk[f][0] = packcvt(p0, p1);
                pk[f][1] = packcvt(p2, p3);
            }
            l_part[qg] += rsum;

            // redistribute pk -> pb (B-operand fragments) in-register
#pragma unroll
            for (int kb = 0; kb < 2; kb++) {
                unsigned a = pk[2 * kb][0], c = pk[2 * kb + 1][0];
                plswap32(a, c); plswap16(a, c);
                pb[qg][kb].u[0] = a; pb[qg][kb].u[2] = c;
                unsigned bb = pk[2 * kb][1], d = pk[2 * kb + 1][1];
                plswap32(bb, d); plswap16(bb, d);
                pb[qg][kb].u[1] = bb; pb[qg][kb].u[3] = d;
            }
        }

        // PV: O^T += V^T-frag x P^T-frag
        __builtin_amdgcn_s_setprio(1);
#pragma unroll
        for (int dt = 0; dt < 4; dt++) {
            int rr = dt * 16 + lr;
            const short* vp = &Vs[cur][rr * 64];
            bf16x8 va0 = *(const bf16x8*)(vp + ((lg ^ (rr & 7)) * 8));
            bf16x8 va1 = *(const bf16x8*)(vp + (((4 + lg) ^ (rr & 7)) * 8));
#pragma unroll
            for (int qg = 0; qg < 2; qg++) {
                ao[qg][dt] = MFMA16(va0, pb[qg][0].v, ao[qg][dt]);
                ao[qg][dt] = MFMA16(va1, pb[qg][1].v, ao[qg][dt]);
            }
        }
        __builtin_amdgcn_s_setprio(0);

        if (kt < 15) {
            if (kt < 13)      asm volatile("s_waitcnt vmcnt(4)" ::: "memory");
            else if (kt == 13) asm volatile("s_waitcnt vmcnt(2)" ::: "memory");
            else               asm volatile("s_waitcnt vmcnt(0)" ::: "memory");
            __builtin_amdgcn_s_barrier();
            __builtin_amdgcn_sched_barrier(0);
        }
    }

    // epilogue: one cross-lane l reduction, normalize, store 8B chunks
#pragma unroll
    for (int qg = 0; qg < 2; qg++) {
        float inv = 1.0f / redsum_lg(l_part[qg]);
        int qglob = qt * 256 + qhalf * 128 + w4 * 32 + qg * 16 + lr;
        size_t ob = ((size_t)b * N_ + qglob) * 512 + h * 64 + lg * 4;
#pragma unroll
        for (int dt = 0; dt < 4; dt++) {
            uint2 val;
            val.x = packcvt(ao[qg][dt][0] * inv, ao[qg][dt][1] * inv);
            val.y = packcvt(ao[qg][dt][2] * inv, ao[qg][dt][3] * inv);
            *(uint2*)(attn_out + ob + dt * 16) = val;
        }
    }
}

// ---------------------------------------------------------------- out proj (transposed: M=channels)
// R22/R24 config (measured best): BK=32, 128x128 tiles, grid (128,4), XOR swizzle.
__global__ __launch_bounds__(256) void k_gemm_out(
        const short* __restrict__ A, const short* __restrict__ Bt,
        const float* __restrict__ x, const float* __restrict__ obias, float* __restrict__ out) {
    __shared__ short Asm[128 * 32];
    __shared__ short Bsm[128 * 32];
    int tid = threadIdx.x, wv = tid >> 6, ln = tid & 63;
    int wr = wv >> 1, wc = wv & 1, lr = ln & 15, lg = ln >> 4;
    const short* Ab = A + (size_t)blockIdx.y * 128 * 512;
    const short* Bb = Bt + (size_t)blockIdx.x * 128 * 512;
    f32x4 acc[4][4] = {};
    int srow = ln >> 2, sch = ln & 3;
    int sx = sch ^ ((srow >> 1) & 3);
    for (int kb = 0; kb < 512; kb += 32) {
        int r0 = wv * 32;
        const short* ga = Ab + (size_t)(r0 + srow) * 512 + kb + sx * 8;
        gload16(ga, (void*)(Asm + r0 * 32));
        gload16(ga + 16 * 512, (void*)(Asm + (r0 + 16) * 32));
        const short* gbp = Bb + (size_t)(r0 + srow) * 512 + kb + sx * 8;
        gload16(gbp, (void*)(Bsm + r0 * 32));
        gload16(gbp + 16 * 512, (void*)(Bsm + (r0 + 16) * 32));
        __syncthreads();
        bf16x8 af[4], bfr[4];
#pragma unroll
        for (int m = 0; m < 4; m++) {
            int R = wr * 64 + m * 16 + lr;
            af[m] = *(const bf16x8*)(Asm + R * 32 + (lg ^ ((R >> 1) & 3)) * 8);
        }
#pragma unroll
        for (int f = 0; f < 4; f++) {
            int R = wc * 64 + f * 16 + lr;
            bfr[f] = *(const bf16x8*)(Bsm + R * 32 + (lg ^ ((R >> 1) & 3)) * 8);
        }
#pragma unroll
        for (int m = 0; m < 4; m++)
#pragma unroll
            for (int f = 0; f < 4; f++)
                acc[m][f] = MFMA16(af[m], bfr[f], acc[m][f]);
        __syncthreads();
    }
    int cb = blockIdx.y * 128 + wr * 64, tb = blockIdx.x * 128 + wc * 64;
#pragma unroll
    for (int m = 0; m < 4; m++) {
#pragma unroll
        for (int f = 0; f < 4; f++) {
            int gt = tb + f * 16 + lr;
            int b = gt >> 10, n = gt & 1023;
#pragma unroll
            for (int r = 0; r < 4; r++) {
                int gc = cb + m * 16 + lg * 4 + r;
                size_t ad = ((size_t)b * C_ + gc) * N_ + n;
                out[ad] = acc[m][f][r] + obias[gc] + x[ad];
            }
        }
    }
}

// ---------------------------------------------------------------- launch
extern "C" void kernel_launch(void* const* d_in, const int* in_sizes, int n_in,
                              void* d_out, int out_size, void* d_ws, size_t ws_size,
                              hipStream_t stream) {
    const float* x     = (const float*)d_in[0];
    const float* temb  = (const float*)d_in[1];
    const float* tm_w1 = (const float*)d_in[2];
    const float* tm_b1 = (const float*)d_in[3];
    const float* tm_w2 = (const float*)d_in[4];
    const float* tm_b2 = (const float*)d_in[5];
    const float* qkv_w = (const float*)d_in[6];
    const float* out_w = (const float*)d_in[7];
    const float* out_b = (const float*)d_in[8];
    float* out = (float*)d_out;

    char* ws = (char*)d_ws;
    short*  qkvwT  = (short*)(ws);                 // 1536*512*2  = 1,572,864
    short*  outwT  = (short*)(ws + 1572864);       //  512*512*2  =   524,288
    float4* ropetab= (float4*)(ws + 2097152);      // 1024*32*16  =   524,288
    float*  gb     = (float*)(ws + 2621440);       // 16*1024*4
    short*  tokens = (short*)(ws + 2686976);       // 16384*512*2 = 16,777,216 (also attn_out)
    short*  qr     = (short*)(ws + 19464192);      // 16,777,216
    short*  kr     = (short*)(ws + 36241408);
    short*  vt     = (short*)(ws + 53018624);      // end ~66.6 MB
    short*  attn   = tokens;                        // tokens dead after k_gemm_qkv
    float*  hbuf   = (float*)(ws + 2686976);       // 16*512*4 = 32 KB, inside tokens
                                                   // region (dead until adacln)

    k_prep1<<<dim3(640), dim3(256), 0, stream>>>(qkv_w, out_w, qkvwT, outwT, ropetab,
                                                 temb, tm_w1, tm_b1, hbuf);
    k_mlp2<<<dim3(32, 16), dim3(256), 0, stream>>>(hbuf, tm_w2, tm_b2, gb);
    k_adacln<<<dim3(32, 16), dim3(256), 0, stream>>>(x, gb, tokens);
    k_gemm_qkv<<<dim3(1536), dim3(256), 0, stream>>>(tokens, qkvwT, ropetab, qr, kr, vt);
    k_flash12<<<dim3(128, 4), dim3(512), 0, stream>>>(qr, kr, vt, attn);
    k_gemm_out<<<dim3(128, 4), dim3(256), 0, stream>>>(outwT, attn, x, out_b, out);
}

// Round 29
// 130.783 us; speedup vs baseline: 1.0013x; 1.0013x over previous
//
#include <hip/hip_runtime.h>
#include <stdint.h>
#include <stddef.h>

// Problem constants
#define B_  16
#define C_  512
#define N_  1024    // H*W = 32*32
#define NH  8
#define HD  64

typedef __attribute__((ext_vector_type(8))) short bf16x8;
typedef __attribute__((ext_vector_type(4))) float f32x4;
typedef __attribute__((ext_vector_type(2))) __bf16 bf16x2t;
typedef __attribute__((ext_vector_type(2))) unsigned uint2v;

__device__ __forceinline__ float bf2f(short s) {
    unsigned u = ((unsigned)(unsigned short)s) << 16;
    return __builtin_bit_cast(float, u);
}
// Compiler-visible f32->bf16 (RNE): lowers to v_cvt_pk_bf16_f32 on gfx950.
__device__ __forceinline__ unsigned packcvt(float lo, float hi) {
    bf16x2t v = { (__bf16)lo, (__bf16)hi };
    return __builtin_bit_cast(unsigned, v);
}
__device__ __forceinline__ short f2bf_hw(float f) {
    __bf16 b = (__bf16)f;
    return __builtin_bit_cast(short, b);
}
// Native 2^x (v_exp_f32 IS exp2; denorm flush-to-zero is fine for softmax tails)
__device__ __forceinline__ float fexp2(float x) {
#if __has_builtin(__builtin_amdgcn_exp2f)
    return __builtin_amdgcn_exp2f(x);
#else
    return exp2f(x);
#endif
}
// Two-register half-swaps (gfx950). swap32: a's lanes32-63 <-> b's lanes0-31.
// swap16: a's odd 16-rows <-> b's even 16-rows.
__device__ __forceinline__ void plswap32(unsigned& a, unsigned& b) {
#if __has_builtin(__builtin_amdgcn_permlane32_swap)
    uint2v r = __builtin_amdgcn_permlane32_swap(a, b, false, false);
    a = r.x; b = r.y;
#else
    unsigned ax = (unsigned)__shfl_xor((int)a, 32, 64), bx = (unsigned)__shfl_xor((int)b, 32, 64);
    bool hi = (threadIdx.x & 32) != 0;
    unsigned na = hi ? bx : a, nb = hi ? b : ax;
    a = na; b = nb;
#endif
}
__device__ __forceinline__ void plswap16(unsigned& a, unsigned& b) {
#if __has_builtin(__builtin_amdgcn_permlane16_swap)
    uint2v r = __builtin_amdgcn_permlane16_swap(a, b, false, false);
    a = r.x; b = r.y;
#else
    unsigned ax = (unsigned)__shfl_xor((int)a, 16, 64), bx = (unsigned)__shfl_xor((int)b, 16, 64);
    bool hi = (threadIdx.x & 16) != 0;
    unsigned na = hi ? bx : a, nb = hi ? b : ax;
    a = na; b = nb;
#endif
}
__device__ __forceinline__ float bcf(unsigned u) { return __builtin_bit_cast(float, u); }
__device__ __forceinline__ unsigned bcu(float f) { return __builtin_bit_cast(unsigned, f); }
// butterfly reduce across lane bits 4,5 (the 4 lane-groups): result valid in all lanes
__device__ __forceinline__ float redsum_lg(float x) {
    unsigned a = bcu(x), b = a; plswap32(a, b);
    float s = bcf(a) + bcf(b);
    a = bcu(s); b = a; plswap16(a, b);
    return bcf(a) + bcf(b);
}

#define MFMA16(a, b, c) __builtin_amdgcn_mfma_f32_16x16x32_bf16((a), (b), (c), 0, 0, 0)

typedef __attribute__((address_space(3))) unsigned int lds_u32;
typedef __attribute__((address_space(1))) unsigned int glb_u32;
// dest = wave-uniform LDS base + lane*16 (m104); global src is per-lane.
__device__ __forceinline__ void gload16(const void* g, void* l) {
    __builtin_amdgcn_global_load_lds((const glb_u32*)g, (lds_u32*)l, 16, 0, 0);
}

// ---------------------------------------------------------------- prep + mlp1 (merged, R27 config)
// bid < 192: qkv_w transpose; bid < 256: out_w transpose; bid < 384: rope
// table; bid >= 384 (256 blocks): mlp1 h = silu(temb@w1+b1). Halves are
// data-independent -> one dispatch boundary removed, work overlaps on CUs.
__global__ __launch_bounds__(256) void k_prep1(
        const float* __restrict__ qkv_w, const float* __restrict__ out_w,
        short* __restrict__ qkvwT, short* __restrict__ outwT,
        float4* __restrict__ ropetab,
        const float* __restrict__ temb, const float* __restrict__ w1,
        const float* __restrict__ b1, float* __restrict__ h) {
    int bid = blockIdx.x, tid = threadIdx.x;
    __shared__ float ts[64][65];
    __shared__ float ps[8][32];
    if (bid < 256) {
        const float* src; short* dst; int J, jt, kt;
        if (bid < 192) { src = qkv_w; dst = qkvwT; J = 1536; jt = (bid % 24) * 64; kt = (bid / 24) * 64; }
        else { int b2 = bid - 192; src = out_w; dst = outwT; J = 512; jt = (b2 & 7) * 64; kt = (b2 >> 3) * 64; }
        int r = tid >> 4, c4 = (tid & 15) * 4;
        for (int rr = 0; rr < 64; rr += 16) {
            float4 v = *(const float4*)(src + (size_t)(kt + rr + r) * J + jt + c4);
            ts[c4 + 0][rr + r] = v.x;
            ts[c4 + 1][rr + r] = v.y;
            ts[c4 + 2][rr + r] = v.z;
            ts[c4 + 3][rr + r] = v.w;
        }
        __syncthreads();
        int jr = tid >> 2, kc = (tid & 3) * 16;
        unsigned w[8];
#pragma unroll
        for (int i = 0; i < 8; i++) w[i] = packcvt(ts[jr][kc + 2 * i], ts[jr][kc + 2 * i + 1]);
        short* dp = dst + (size_t)(jt + jr) * 512 + kt + kc;
        *(uint4*)(dp)     = make_uint4(w[0], w[1], w[2], w[3]);
        *(uint4*)(dp + 8) = make_uint4(w[4], w[5], w[6], w[7]);
    } else if (bid < 384) {
        int idx = (bid - 256) * 256 + tid;       // 32768 entries
        int n = idx >> 5, dq = idx & 31, i = dq & 15;
        float w = powf(100.0f, -(float)i * (1.0f / 16.0f));
        float y = (float)(n >> 5), xx = (float)(n & 31);
        ropetab[idx] = make_float4(cosf(y * w), sinf(y * w), cosf(xx * w), sinf(xx * w));
    } else {
        // mlp1: rem = bid-384; jt = rem%16, b = rem/16
        int rem = bid - 384;
        int jt = rem & 15, b = rem >> 4;
        int jl = tid & 31, j = jt * 32 + jl, ks = tid >> 5;
        float* tl = &ts[0][0];                    // reuse LDS (512 floats)
        tl[tid] = temb[b * 512 + tid];
        tl[tid + 256] = temb[b * 512 + tid + 256];
        __syncthreads();
        float acc = 0.f;
        const float* wp = w1 + (size_t)(ks * 64) * 512 + j;
#pragma unroll 8
        for (int kk = 0; kk < 64; kk++) acc += tl[ks * 64 + kk] * wp[(size_t)kk * 512];
        ps[ks][jl] = acc;
        __syncthreads();
        if (tid < 32) {
            float s = ((ps[0][tid] + ps[1][tid]) + (ps[2][tid] + ps[3][tid]))
                    + ((ps[4][tid] + ps[5][tid]) + (ps[6][tid] + ps[7][tid]));
            s += b1[jt * 32 + tid];
            h[b * 512 + jt * 32 + tid] = s / (1.0f + __expf(-s));
        }
    }
}

__global__ __launch_bounds__(256) void k_mlp2(
        const float* __restrict__ h, const float* __restrict__ w2, const float* __restrict__ b2,
        float* __restrict__ gbout) {
    int b = blockIdx.y, jt = blockIdx.x, tid = threadIdx.x;
    int jl = tid & 31, j = jt * 32 + jl, ks = tid >> 5;
    __shared__ float hl[512];
    __shared__ float ps[8][32];
    hl[tid] = h[b * 512 + tid];
    hl[tid + 256] = h[b * 512 + tid + 256];
    __syncthreads();
    float acc = 0.f;
    const float* wp = w2 + (size_t)(ks * 64) * 1024 + j;
#pragma unroll 8
    for (int kk = 0; kk < 64; kk++) acc += hl[ks * 64 + kk] * wp[(size_t)kk * 1024];
    ps[ks][jl] = acc;
    __syncthreads();
    if (tid < 32) {
        float s = ((ps[0][tid] + ps[1][tid]) + (ps[2][tid] + ps[3][tid]))
                + ((ps[4][tid] + ps[5][tid]) + (ps[6][tid] + ps[7][tid]));
        gbout[b * 1024 + jt * 32 + tid] = s + b2[jt * 32 + tid];
    }
}

// ---------------------------------------------------------------- AdaCLN -> tokens bf16 (B,N,C)
// R27 config (64-pixel tiles; 32-pixel split was neutral in R28).
__global__ __launch_bounds__(256) void k_adacln(
        const float* __restrict__ x, const float* __restrict__ gb, short* __restrict__ tokens) {
    int b = blockIdx.y, n0 = blockIdx.x * 64;
    int tid = threadIdx.x;
    const float* xb = x + (size_t)b * C_ * N_;
    __shared__ float4 rs4[16][16], rq4[16][16];
    __shared__ float mean_s[64], rstd_s[64];
    __shared__ float xs[64][65];

    // pass 1: stats. quad q = tid&15 (pixels n0+4q..4q+3), slice s = tid>>4 (32 ch)
    {
        int q = tid & 15, s = tid >> 4;
        float4 sum = make_float4(0.f, 0.f, 0.f, 0.f);
        float4 sq  = make_float4(0.f, 0.f, 0.f, 0.f);
        const float* xp = xb + (size_t)(s * 32) * N_ + n0 + q * 4;
#pragma unroll 8
        for (int ci = 0; ci < 32; ci++) {
            float4 v = *(const float4*)(xp + (size_t)ci * N_);
            sum.x += v.x; sum.y += v.y; sum.z += v.z; sum.w += v.w;
            sq.x += v.x * v.x; sq.y += v.y * v.y; sq.z += v.z * v.z; sq.w += v.w * v.w;
        }
        rs4[s][q] = sum; rq4[s][q] = sq;
    }
    __syncthreads();
    if (tid < 64) {
        int q = tid >> 2, j = tid & 3;
        float s1 = 0.f, s2 = 0.f;
#pragma unroll
        for (int s = 0; s < 16; s++) {
            float4 a = rs4[s][q], c = rq4[s][q];
            s1 += (&a.x)[j];
            s2 += (&c.x)[j];
        }
        float mu = s1 * (1.0f / 512.0f);
        float var = s2 * (1.0f / 512.0f) - mu * mu;
        mean_s[tid] = mu;
        rstd_s[tid] = rsqrtf(var + 1e-6f);
    }
    const float* gam = gb + b * 1024;
    const float* bet = gam + 512;
    int ch = tid & 7;
    for (int ct = 0; ct < 8; ct++) {
        __syncthreads();
#pragma unroll
        for (int itr = 0; itr < 4; itr++) {
            int cl = itr * 16 + (tid >> 4), q = tid & 15;
            float4 v = *(const float4*)(xb + (size_t)(ct * 64 + cl) * N_ + n0 + q * 4);
            xs[cl][q * 4 + 0] = v.x;
            xs[cl][q * 4 + 1] = v.y;
            xs[cl][q * 4 + 2] = v.z;
            xs[cl][q * 4 + 3] = v.w;
        }
        __syncthreads();
#pragma unroll
        for (int pp = 0; pp < 2; pp++) {
            int p = pp * 32 + (tid >> 3);
            float mu = mean_s[p], rt = rstd_s[p];
            float v[8];
#pragma unroll
            for (int j = 0; j < 8; j++) {
                int c = ct * 64 + ch * 8 + j;
                v[j] = (xs[ch * 8 + j][p] - mu) * rt * (1.0f + gam[c]) + bet[c];
            }
            uint4 ov = make_uint4(packcvt(v[0], v[1]), packcvt(v[2], v[3]),
                                  packcvt(v[4], v[5]), packcvt(v[6], v[7]));
            *(uint4*)(tokens + ((size_t)(b * N_ + n0 + p)) * C_ + ct * 64 + ch * 8) = ov;
        }
    }
}

// ---------------------------------------------------------------- QKV GEMM + fused RoPE
// BK=64 (R21/R22-measured win for this kernel: 1536 blocks -> ~5-6/CU TLP),
// XCD swizzle (T1), LDS chunk XOR-swizzle (bank-conflict-free, R18->R19).
__global__ __launch_bounds__(256) void k_gemm_qkv(
        const short* __restrict__ A, const short* __restrict__ Bt,
        const float4* __restrict__ ropetab,
        short* __restrict__ qr, short* __restrict__ kr, short* __restrict__ vt) {
    __shared__ short Asm[128 * 64];
    __shared__ short Bsm[128 * 64];
    int wgid = blockIdx.x;
    int orig = (wgid & 7) * 192 + (wgid >> 3);   // bijective: 1536 = 8*192
    int bx = orig % 12, by = orig / 12;
    int tid = threadIdx.x, wv = tid >> 6, ln = tid & 63;
    int wr = wv >> 1, wc = wv & 1, lr = ln & 15, lg = ln >> 4;
    const short* Ab = A + (size_t)by * 128 * 512;
    const short* Bb = Bt + (size_t)bx * 128 * 512;
    f32x4 acc[4][4] = {};
    int lrow = ln >> 3, lch = ln & 7;
    int schx = (lch ^ (lrow & 7)) * 8;           // swizzled source col (shorts)
    for (int kt = 0; kt < 8; kt++) {
        int kb = kt * 64;
#pragma unroll
        for (int g = 0; g < 4; g++) {
            int row = wv * 32 + g * 8 + lrow;
            gload16(Ab + (size_t)row * 512 + kb + schx, (void*)(Asm + (wv * 32 + g * 8) * 64));
            gload16(Bb + (size_t)row * 512 + kb + schx, (void*)(Bsm + (wv * 32 + g * 8) * 64));
        }
        __syncthreads();
        bf16x8 af[2][4], bfr[2][4];
#pragma unroll
        for (int kk = 0; kk < 2; kk++) {
#pragma unroll
            for (int m = 0; m < 4; m++) {
                int R = wr * 64 + m * 16 + lr;
                af[kk][m] = *(const bf16x8*)(Asm + R * 64 + ((lg + kk * 4) ^ (R & 7)) * 8);
            }
#pragma unroll
            for (int f = 0; f < 4; f++) {
                int R = wc * 64 + f * 16 + lr;
                bfr[kk][f] = *(const bf16x8*)(Bsm + R * 64 + ((lg + kk * 4) ^ (R & 7)) * 8);
            }
        }
#pragma unroll
        for (int kk = 0; kk < 2; kk++)
#pragma unroll
            for (int m = 0; m < 4; m++)
#pragma unroll
                for (int f = 0; f < 4; f++)
                    acc[m][f] = MFMA16(af[kk][m], bfr[kk][f], acc[m][f]);
        __syncthreads();
    }
    int mbase = by * 128;
    int sec = bx >> 2;
    int h = (2 * bx + wc) & 7;
    if (sec < 2) {
        short* dst0 = (sec == 0) ? qr : kr;
#pragma unroll
        for (int m = 0; m < 4; m++) {
            int gmb = mbase + wr * 64 + m * 16 + lg * 4;
#pragma unroll
            for (int r = 0; r < 4; r++) {
                int gm = gmb + r; int b = gm >> 10, n = gm & 1023;
                short* rowp = dst0 + (((size_t)b * NH + h) * N_ + n) * HD;
                const float4* tr = ropetab + n * 32;
#pragma unroll
                for (int f2 = 0; f2 < 2; f2++) {
                    int d_lo = f2 * 16 + lr;
                    float4 t = tr[d_lo];
                    float a = acc[m][f2][r], bb2 = acc[m][f2 + 2][r];
                    rowp[d_lo]      = f2bf_hw(a * t.x - bb2 * t.y);
                    rowp[d_lo + 32] = f2bf_hw(bb2 * t.z + a * t.w);
                }
            }
        }
    } else {
#pragma unroll
        for (int m = 0; m < 4; m++) {
            int gmb = mbase + wr * 64 + m * 16 + lg * 4;
            int b = gmb >> 10, n0 = gmb & 1023;
#pragma unroll
            for (int f = 0; f < 4; f++) {
                int d = f * 16 + lr;
                uint2 val;
                val.x = packcvt(acc[m][f][0], acc[m][f][1]);
                val.y = packcvt(acc[m][f][2], acc[m][f][3]);
                *(uint2*)(vt + (((size_t)b * NH + h) * HD + d) * N_ + n0) = val;
            }
        }
    }
}

// ---------------------------------------------------------------- flash attention v12 (final, depth 4)
// Pipeline depth 4 (Ks[4]/Vs[4], 64 KB LDS; measured best: depth 3 -6.6us,
// 3->4 -1.9us, 4->5 neutral). Grid (bh=128, qt=4): 128 == 0 mod 8 -> all 4
// qt-blocks of a bh on one XCD. 8-wave blocks, 2 q-tiles each. Counted-vmcnt
// (T4), setprio around MFMA (T5, ~-5us), fixed-shift exp2 softmax, permlane
// P-redistribution (T12), XOR-swizzled K/V staging (T2 via m173 pattern).
__global__ __launch_bounds__(512) void k_flash12(
        const short* __restrict__ qr, const short* __restrict__ kr, const short* __restrict__ vt,
        short* __restrict__ attn_out) {
    __shared__ short Ks[4][4096];        // [k=64][d=64] chunk-swizzled
    __shared__ short Vs[4][4096];        // [d=64][k=64] chunk-swizzled
    int bh = blockIdx.x, b = bh >> 3, h = bh & 7;
    int qt = blockIdx.y;
    int tid = threadIdx.x, wv = tid >> 6, ln = tid & 63;
    int lr = ln & 15, lg = ln >> 4;
    int qhalf = wv >> 2, w4 = wv & 3;
    const short* Qb = qr + ((size_t)bh * N_ + qt * 256 + qhalf * 128 + w4 * 32) * HD;
    const short* Kb = kr + (size_t)bh * N_ * HD;
    const short* Vb = vt + (size_t)bh * HD * N_;

    // Q as B-operand fragments, pre-scaled by 0.125*log2(e): S lands in log2 domain
    const float QSCALE = 0.125f * 1.44269504f;
    bf16x8 qf[2][2];
#pragma unroll
    for (int qg = 0; qg < 2; qg++)
#pragma unroll
        for (int hf = 0; hf < 2; hf++) {
            bf16x8 raw = *(const bf16x8*)(Qb + (qg * 16 + lr) * 64 + hf * 32 + lg * 8);
            bf16x8 sc;
#pragma unroll
            for (int j = 0; j < 8; j++) sc[j] = f2bf_hw(bf2f(raw[j]) * QSCALE);
            qf[qg][hf] = sc;
        }

    int srow = ln >> 3, cpos = ln & 7;
    int rloc = wv * 8 + srow;            // 0..63: this wave's K-row / V-row
    int csrc = cpos ^ (srow & 7);

    float l_part[2] = {0.f, 0.f};
    f32x4 ao[2][4] = {};

    // drain Q vector-loads so vmcnt counts only staging gloads from here on
    asm volatile("s_waitcnt vmcnt(0)" ::: "memory");
    __builtin_amdgcn_sched_barrier(0);

    // stage tiles 0,1,2 (2 gloads/wave each)
#pragma unroll
    for (int t0 = 0; t0 < 3; t0++) {
        gload16(Kb + ((size_t)(t0 * 64 + rloc)) * 64 + csrc * 8,
                (void*)&Ks[t0][rloc * 64]);
        gload16(Vb + ((size_t)rloc) * 1024 + t0 * 64 + csrc * 8,
                (void*)&Vs[t0][rloc * 64]);
    }
    asm volatile("s_waitcnt vmcnt(4)" ::: "memory");   // tile 0 complete
    __builtin_amdgcn_s_barrier();
    __builtin_amdgcn_sched_barrier(0);

    for (int kt = 0; kt < 16; kt++) {
        int cur = kt & 3;
        if (kt < 13) {
            int nxt = (kt + 3) & 3, ktn = kt + 3;
            gload16(Kb + ((size_t)(ktn * 64 + rloc)) * 64 + csrc * 8,
                    (void*)&Ks[nxt][rloc * 64]);
            gload16(Vb + ((size_t)rloc) * 1024 + ktn * 64 + csrc * 8,
                    (void*)&Vs[nxt][rloc * 64]);
        }

        // QK^T (swapped): sT[qg][f][r] = S^T[k = f*16+lg*4+r][q = qg*16+lr] (log2 domain)
        f32x4 sT[2][4];
        __builtin_amdgcn_s_setprio(1);
#pragma unroll
        for (int f = 0; f < 4; f++) {
            int r = f * 16 + lr;
            const short* kp = &Ks[cur][r * 64];
            bf16x8 ka  = *(const bf16x8*)(kp + ((lg ^ (r & 7)) * 8));
            bf16x8 kb2 = *(const bf16x8*)(kp + (((4 + lg) ^ (r & 7)) * 8));
#pragma unroll
            for (int qg = 0; qg < 2; qg++) {
                f32x4 s = {};
                s = MFMA16(ka, qf[qg][0], s);
                s = MFMA16(kb2, qf[qg][1], s);
                sT[qg][f] = s;
            }
        }
        __builtin_amdgcn_s_setprio(0);

        // fixed-shift softmax: p = exp2(s) directly; l accumulated per-lane
        union U4 { unsigned u[4]; bf16x8 v; };
        U4 pb[2][2];
#pragma unroll
        for (int qg = 0; qg < 2; qg++) {
            float rsum = 0.f;
            unsigned pk[4][2];
#pragma unroll
            for (int f = 0; f < 4; f++) {
                float p0 = fexp2(sT[qg][f][0]);
                float p1 = fexp2(sT[qg][f][1]);
                float p2 = fexp2(sT[qg][f][2]);
                float p3 = fexp2(sT[qg][f][3]);
                rsum += (p0 + p1) + (p2 + p3);
                pk[f][0] = packcvt(p0, p1);
                pk[f][1] = packcvt(p2, p3);
            }
            l_part[qg] += rsum;

            // redistribute pk -> pb (B-operand fragments) in-register
#pragma unroll
            for (int kb = 0; kb < 2; kb++) {
                unsigned a = pk[2 * kb][0], c = pk[2 * kb + 1][0];
                plswap32(a, c); plswap16(a, c);
                pb[qg][kb].u[0] = a; pb[qg][kb].u[2] = c;
                unsigned bb = pk[2 * kb][1], d = pk[2 * kb + 1][1];
                plswap32(bb, d); plswap16(bb, d);
                pb[qg][kb].u[1] = bb; pb[qg][kb].u[3] = d;
            }
        }

        // PV: O^T += V^T-frag x P^T-frag
        __builtin_amdgcn_s_setprio(1);
#pragma unroll
        for (int dt = 0; dt < 4; dt++) {
            int rr = dt * 16 + lr;
            const short* vp = &Vs[cur][rr * 64];
            bf16x8 va0 = *(const bf16x8*)(vp + ((lg ^ (rr & 7)) * 8));
            bf16x8 va1 = *(const bf16x8*)(vp + (((4 + lg) ^ (rr & 7)) * 8));
#pragma unroll
            for (int qg = 0; qg < 2; qg++) {
                ao[qg][dt] = MFMA16(va0, pb[qg][0].v, ao[qg][dt]);
                ao[qg][dt] = MFMA16(va1, pb[qg][1].v, ao[qg][dt]);
            }
        }
        __builtin_amdgcn_s_setprio(0);

        if (kt < 15) {
            if (kt < 13)      asm volatile("s_waitcnt vmcnt(4)" ::: "memory");
            else if (kt == 13) asm volatile("s_waitcnt vmcnt(2)" ::: "memory");
            else               asm volatile("s_waitcnt vmcnt(0)" ::: "memory");
            __builtin_amdgcn_s_barrier();
            __builtin_amdgcn_sched_barrier(0);
        }
    }

    // epilogue: one cross-lane l reduction, normalize, store 8B chunks
#pragma unroll
    for (int qg = 0; qg < 2; qg++) {
        float inv = 1.0f / redsum_lg(l_part[qg]);
        int qglob = qt * 256 + qhalf * 128 + w4 * 32 + qg * 16 + lr;
        size_t ob = ((size_t)b * N_ + qglob) * 512 + h * 64 + lg * 4;
#pragma unroll
        for (int dt = 0; dt < 4; dt++) {
            uint2 val;
            val.x = packcvt(ao[qg][dt][0] * inv, ao[qg][dt][1] * inv);
            val.y = packcvt(ao[qg][dt][2] * inv, ao[qg][dt][3] * inv);
            *(uint2*)(attn_out + ob + dt * 16) = val;
        }
    }
}

// ---------------------------------------------------------------- out proj (transposed: M=channels)
// Final config: BK=32, 128x128 tiles, grid (128,4), XOR swizzle (both BK=64
// and 128x64 split regressed -> latency-structural floor for this kernel).
__global__ __launch_bounds__(256) void k_gemm_out(
        const short* __restrict__ A, const short* __restrict__ Bt,
        const float* __restrict__ x, const float* __restrict__ obias, float* __restrict__ out) {
    __shared__ short Asm[128 * 32];
    __shared__ short Bsm[128 * 32];
    int tid = threadIdx.x, wv = tid >> 6, ln = tid & 63;
    int wr = wv >> 1, wc = wv & 1, lr = ln & 15, lg = ln >> 4;
    const short* Ab = A + (size_t)blockIdx.y * 128 * 512;
    const short* Bb = Bt + (size_t)blockIdx.x * 128 * 512;
    f32x4 acc[4][4] = {};
    int srow = ln >> 2, sch = ln & 3;
    int sx = sch ^ ((srow >> 1) & 3);
    for (int kb = 0; kb < 512; kb += 32) {
        int r0 = wv * 32;
        const short* ga = Ab + (size_t)(r0 + srow) * 512 + kb + sx * 8;
        gload16(ga, (void*)(Asm + r0 * 32));
        gload16(ga + 16 * 512, (void*)(Asm + (r0 + 16) * 32));
        const short* gbp = Bb + (size_t)(r0 + srow) * 512 + kb + sx * 8;
        gload16(gbp, (void*)(Bsm + r0 * 32));
        gload16(gbp + 16 * 512, (void*)(Bsm + (r0 + 16) * 32));
        __syncthreads();
        bf16x8 af[4], bfr[4];
#pragma unroll
        for (int m = 0; m < 4; m++) {
            int R = wr * 64 + m * 16 + lr;
            af[m] = *(const bf16x8*)(Asm + R * 32 + (lg ^ ((R >> 1) & 3)) * 8);
        }
#pragma unroll
        for (int f = 0; f < 4; f++) {
            int R = wc * 64 + f * 16 + lr;
            bfr[f] = *(const bf16x8*)(Bsm + R * 32 + (lg ^ ((R >> 1) & 3)) * 8);
        }
#pragma unroll
        for (int m = 0; m < 4; m++)
#pragma unroll
            for (int f = 0; f < 4; f++)
                acc[m][f] = MFMA16(af[m], bfr[f], acc[m][f]);
        __syncthreads();
    }
    int cb = blockIdx.y * 128 + wr * 64, tb = blockIdx.x * 128 + wc * 64;
#pragma unroll
    for (int m = 0; m < 4; m++) {
#pragma unroll
        for (int f = 0; f < 4; f++) {
            int gt = tb + f * 16 + lr;
            int b = gt >> 10, n = gt & 1023;
#pragma unroll
            for (int r = 0; r < 4; r++) {
                int gc = cb + m * 16 + lg * 4 + r;
                size_t ad = ((size_t)b * C_ + gc) * N_ + n;
                out[ad] = acc[m][f][r] + obias[gc] + x[ad];
            }
        }
    }
}

// ---------------------------------------------------------------- launch
extern "C" void kernel_launch(void* const* d_in, const int* in_sizes, int n_in,
                              void* d_out, int out_size, void* d_ws, size_t ws_size,
                              hipStream_t stream) {
    const float* x     = (const float*)d_in[0];
    const float* temb  = (const float*)d_in[1];
    const float* tm_w1 = (const float*)d_in[2];
    const float* tm_b1 = (const float*)d_in[3];
    const float* tm_w2 = (const float*)d_in[4];
    const float* tm_b2 = (const float*)d_in[5];
    const float* qkv_w = (const float*)d_in[6];
    const float* out_w = (const float*)d_in[7];
    const float* out_b = (const float*)d_in[8];
    float* out = (float*)d_out;

    char* ws = (char*)d_ws;
    short*  qkvwT  = (short*)(ws);                 // 1536*512*2  = 1,572,864
    short*  outwT  = (short*)(ws + 1572864);       //  512*512*2  =   524,288
    float4* ropetab= (float4*)(ws + 2097152);      // 1024*32*16  =   524,288
    float*  gb     = (float*)(ws + 2621440);       // 16*1024*4
    short*  tokens = (short*)(ws + 2686976);       // 16384*512*2 = 16,777,216 (also attn_out)
    short*  qr     = (short*)(ws + 19464192);      // 16,777,216
    short*  kr     = (short*)(ws + 36241408);
    short*  vt     = (short*)(ws + 53018624);      // end ~66.6 MB
    short*  attn   = tokens;                        // tokens dead after k_gemm_qkv
    float*  hbuf   = (float*)(ws + 2686976);       // 16*512*4 = 32 KB, inside tokens
                                                   // region (dead until adacln)

    k_prep1<<<dim3(640), dim3(256), 0, stream>>>(qkv_w, out_w, qkvwT, outwT, ropetab,
                                                 temb, tm_w1, tm_b1, hbuf);
    k_mlp2<<<dim3(32, 16), dim3(256), 0, stream>>>(hbuf, tm_w2, tm_b2, gb);
    k_adacln<<<dim3(16, 16), dim3(256), 0, stream>>>(x, gb, tokens);
    k_gemm_qkv<<<dim3(1536), dim3(256), 0, stream>>>(tokens, qkvwT, ropetab, qr, kr, vt);
    k_flash12<<<dim3(128, 4), dim3(512), 0, stream>>>(qr, kr, vt, attn);
    k_gemm_out<<<dim3(128, 4), dim3(256), 0, stream>>>(outwT, attn, x, out_b, out);
}

// Round 30
// 130.077 us; speedup vs baseline: 1.0068x; 1.0054x over previous
//
#include <hip/hip_runtime.h>
#include <stdint.h>
#include <stddef.h>

// Problem constants
#define B_  16
#define C_  512
#define N_  1024    // H*W = 32*32
#define NH  8
#define HD  64

typedef __attribute__((ext_vector_type(8))) short bf16x8;
typedef __attribute__((ext_vector_type(4))) float f32x4;
typedef __attribute__((ext_vector_type(2))) __bf16 bf16x2t;
typedef __attribute__((ext_vector_type(2))) unsigned uint2v;

__device__ __forceinline__ float bf2f(short s) {
    unsigned u = ((unsigned)(unsigned short)s) << 16;
    return __builtin_bit_cast(float, u);
}
// Compiler-visible f32->bf16 (RNE): lowers to v_cvt_pk_bf16_f32 on gfx950.
__device__ __forceinline__ unsigned packcvt(float lo, float hi) {
    bf16x2t v = { (__bf16)lo, (__bf16)hi };
    return __builtin_bit_cast(unsigned, v);
}
__device__ __forceinline__ short f2bf_hw(float f) {
    __bf16 b = (__bf16)f;
    return __builtin_bit_cast(short, b);
}
// Native 2^x (v_exp_f32 IS exp2; denorm flush-to-zero is fine for softmax tails)
__device__ __forceinline__ float fexp2(float x) {
#if __has_builtin(__builtin_amdgcn_exp2f)
    return __builtin_amdgcn_exp2f(x);
#else
    return exp2f(x);
#endif
}
// Two-register half-swaps (gfx950). swap32: a's lanes32-63 <-> b's lanes0-31.
// swap16: a's odd 16-rows <-> b's even 16-rows.
__device__ __forceinline__ void plswap32(unsigned& a, unsigned& b) {
#if __has_builtin(__builtin_amdgcn_permlane32_swap)
    uint2v r = __builtin_amdgcn_permlane32_swap(a, b, false, false);
    a = r.x; b = r.y;
#else
    unsigned ax = (unsigned)__shfl_xor((int)a, 32, 64), bx = (unsigned)__shfl_xor((int)b, 32, 64);
    bool hi = (threadIdx.x & 32) != 0;
    unsigned na = hi ? bx : a, nb = hi ? b : ax;
    a = na; b = nb;
#endif
}
__device__ __forceinline__ void plswap16(unsigned& a, unsigned& b) {
#if __has_builtin(__builtin_amdgcn_permlane16_swap)
    uint2v r = __builtin_amdgcn_permlane16_swap(a, b, false, false);
    a = r.x; b = r.y;
#else
    unsigned ax = (unsigned)__shfl_xor((int)a, 16, 64), bx = (unsigned)__shfl_xor((int)b, 16, 64);
    bool hi = (threadIdx.x & 16) != 0;
    unsigned na = hi ? bx : a, nb = hi ? b : ax;
    a = na; b = nb;
#endif
}
__device__ __forceinline__ float bcf(unsigned u) { return __builtin_bit_cast(float, u); }
__device__ __forceinline__ unsigned bcu(float f) { return __builtin_bit_cast(unsigned, f); }
// butterfly reduce across lane bits 4,5 (the 4 lane-groups): result valid in all lanes
__device__ __forceinline__ float redsum_lg(float x) {
    unsigned a = bcu(x), b = a; plswap32(a, b);
    float s = bcf(a) + bcf(b);
    a = bcu(s); b = a; plswap16(a, b);
    return bcf(a) + bcf(b);
}

#define MFMA16(a, b, c) __builtin_amdgcn_mfma_f32_16x16x32_bf16((a), (b), (c), 0, 0, 0)

typedef __attribute__((address_space(3))) unsigned int lds_u32;
typedef __attribute__((address_space(1))) unsigned int glb_u32;
// dest = wave-uniform LDS base + lane*16 (m104); global src is per-lane.
__device__ __forceinline__ void gload16(const void* g, void* l) {
    __builtin_amdgcn_global_load_lds((const glb_u32*)g, (lds_u32*)l, 16, 0, 0);
}

// ---------------------------------------------------------------- prep + mlp1 (merged, R27 config)
// bid < 192: qkv_w transpose; bid < 256: out_w transpose; bid < 384: rope
// table; bid >= 384 (256 blocks): mlp1 h = silu(temb@w1+b1). Halves are
// data-independent -> one dispatch boundary removed, work overlaps on CUs.
__global__ __launch_bounds__(256) void k_prep1(
        const float* __restrict__ qkv_w, const float* __restrict__ out_w,
        short* __restrict__ qkvwT, short* __restrict__ outwT,
        float4* __restrict__ ropetab,
        const float* __restrict__ temb, const float* __restrict__ w1,
        const float* __restrict__ b1, float* __restrict__ h) {
    int bid = blockIdx.x, tid = threadIdx.x;
    __shared__ float ts[64][65];
    __shared__ float ps[8][32];
    if (bid < 256) {
        const float* src; short* dst; int J, jt, kt;
        if (bid < 192) { src = qkv_w; dst = qkvwT; J = 1536; jt = (bid % 24) * 64; kt = (bid / 24) * 64; }
        else { int b2 = bid - 192; src = out_w; dst = outwT; J = 512; jt = (b2 & 7) * 64; kt = (b2 >> 3) * 64; }
        int r = tid >> 4, c4 = (tid & 15) * 4;
        for (int rr = 0; rr < 64; rr += 16) {
            float4 v = *(const float4*)(src + (size_t)(kt + rr + r) * J + jt + c4);
            ts[c4 + 0][rr + r] = v.x;
            ts[c4 + 1][rr + r] = v.y;
            ts[c4 + 2][rr + r] = v.z;
            ts[c4 + 3][rr + r] = v.w;
        }
        __syncthreads();
        int jr = tid >> 2, kc = (tid & 3) * 16;
        unsigned w[8];
#pragma unroll
        for (int i = 0; i < 8; i++) w[i] = packcvt(ts[jr][kc + 2 * i], ts[jr][kc + 2 * i + 1]);
        short* dp = dst + (size_t)(jt + jr) * 512 + kt + kc;
        *(uint4*)(dp)     = make_uint4(w[0], w[1], w[2], w[3]);
        *(uint4*)(dp + 8) = make_uint4(w[4], w[5], w[6], w[7]);
    } else if (bid < 384) {
        int idx = (bid - 256) * 256 + tid;       // 32768 entries
        int n = idx >> 5, dq = idx & 31, i = dq & 15;
        float w = powf(100.0f, -(float)i * (1.0f / 16.0f));
        float y = (float)(n >> 5), xx = (float)(n & 31);
        ropetab[idx] = make_float4(cosf(y * w), sinf(y * w), cosf(xx * w), sinf(xx * w));
    } else {
        // mlp1: rem = bid-384; jt = rem%16, b = rem/16
        int rem = bid - 384;
        int jt = rem & 15, b = rem >> 4;
        int jl = tid & 31, j = jt * 32 + jl, ks = tid >> 5;
        float* tl = &ts[0][0];                    // reuse LDS (512 floats)
        tl[tid] = temb[b * 512 + tid];
        tl[tid + 256] = temb[b * 512 + tid + 256];
        __syncthreads();
        float acc = 0.f;
        const float* wp = w1 + (size_t)(ks * 64) * 512 + j;
#pragma unroll 8
        for (int kk = 0; kk < 64; kk++) acc += tl[ks * 64 + kk] * wp[(size_t)kk * 512];
        ps[ks][jl] = acc;
        __syncthreads();
        if (tid < 32) {
            float s = ((ps[0][tid] + ps[1][tid]) + (ps[2][tid] + ps[3][tid]))
                    + ((ps[4][tid] + ps[5][tid]) + (ps[6][tid] + ps[7][tid]));
            s += b1[jt * 32 + tid];
            h[b * 512 + jt * 32 + tid] = s / (1.0f + __expf(-s));
        }
    }
}

__global__ __launch_bounds__(256) void k_mlp2(
        const float* __restrict__ h, const float* __restrict__ w2, const float* __restrict__ b2,
        float* __restrict__ gbout) {
    int b = blockIdx.y, jt = blockIdx.x, tid = threadIdx.x;
    int jl = tid & 31, j = jt * 32 + jl, ks = tid >> 5;
    __shared__ float hl[512];
    __shared__ float ps[8][32];
    hl[tid] = h[b * 512 + tid];
    hl[tid + 256] = h[b * 512 + tid + 256];
    __syncthreads();
    float acc = 0.f;
    const float* wp = w2 + (size_t)(ks * 64) * 1024 + j;
#pragma unroll 8
    for (int kk = 0; kk < 64; kk++) acc += hl[ks * 64 + kk] * wp[(size_t)kk * 1024];
    ps[ks][jl] = acc;
    __syncthreads();
    if (tid < 32) {
        float s = ((ps[0][tid] + ps[1][tid]) + (ps[2][tid] + ps[3][tid]))
                + ((ps[4][tid] + ps[5][tid]) + (ps[6][tid] + ps[7][tid]));
        gbout[b * 1024 + jt * 32 + tid] = s + b2[jt * 32 + tid];
    }
}

// ---------------------------------------------------------------- AdaCLN -> tokens bf16 (B,N,C)
// R27 config (64-pixel tiles; 32-pixel split was neutral in R28).
__global__ __launch_bounds__(256) void k_adacln(
        const float* __restrict__ x, const float* __restrict__ gb, short* __restrict__ tokens) {
    int b = blockIdx.y, n0 = blockIdx.x * 64;
    int tid = threadIdx.x;
    const float* xb = x + (size_t)b * C_ * N_;
    __shared__ float4 rs4[16][16], rq4[16][16];
    __shared__ float mean_s[64], rstd_s[64];
    __shared__ float xs[64][65];

    // pass 1: stats. quad q = tid&15 (pixels n0+4q..4q+3), slice s = tid>>4 (32 ch)
    {
        int q = tid & 15, s = tid >> 4;
        float4 sum = make_float4(0.f, 0.f, 0.f, 0.f);
        float4 sq  = make_float4(0.f, 0.f, 0.f, 0.f);
        const float* xp = xb + (size_t)(s * 32) * N_ + n0 + q * 4;
#pragma unroll 8
        for (int ci = 0; ci < 32; ci++) {
            float4 v = *(const float4*)(xp + (size_t)ci * N_);
            sum.x += v.x; sum.y += v.y; sum.z += v.z; sum.w += v.w;
            sq.x += v.x * v.x; sq.y += v.y * v.y; sq.z += v.z * v.z; sq.w += v.w * v.w;
        }
        rs4[s][q] = sum; rq4[s][q] = sq;
    }
    __syncthreads();
    if (tid < 64) {
        int q = tid >> 2, j = tid & 3;
        float s1 = 0.f, s2 = 0.f;
#pragma unroll
        for (int s = 0; s < 16; s++) {
            float4 a = rs4[s][q], c = rq4[s][q];
            s1 += (&a.x)[j];
            s2 += (&c.x)[j];
        }
        float mu = s1 * (1.0f / 512.0f);
        float var = s2 * (1.0f / 512.0f) - mu * mu;
        mean_s[tid] = mu;
        rstd_s[tid] = rsqrtf(var + 1e-6f);
    }
    const float* gam = gb + b * 1024;
    const float* bet = gam + 512;
    int ch = tid & 7;
    for (int ct = 0; ct < 8; ct++) {
        __syncthreads();
#pragma unroll
        for (int itr = 0; itr < 4; itr++) {
            int cl = itr * 16 + (tid >> 4), q = tid & 15;
            float4 v = *(const float4*)(xb + (size_t)(ct * 64 + cl) * N_ + n0 + q * 4);
            xs[cl][q * 4 + 0] = v.x;
            xs[cl][q * 4 + 1] = v.y;
            xs[cl][q * 4 + 2] = v.z;
            xs[cl][q * 4 + 3] = v.w;
        }
        __syncthreads();
#pragma unroll
        for (int pp = 0; pp < 2; pp++) {
            int p = pp * 32 + (tid >> 3);
            float mu = mean_s[p], rt = rstd_s[p];
            float v[8];
#pragma unroll
            for (int j = 0; j < 8; j++) {
                int c = ct * 64 + ch * 8 + j;
                v[j] = (xs[ch * 8 + j][p] - mu) * rt * (1.0f + gam[c]) + bet[c];
            }
            uint4 ov = make_uint4(packcvt(v[0], v[1]), packcvt(v[2], v[3]),
                                  packcvt(v[4], v[5]), packcvt(v[6], v[7]));
            *(uint4*)(tokens + ((size_t)(b * N_ + n0 + p)) * C_ + ct * 64 + ch * 8) = ov;
        }
    }
}

// ---------------------------------------------------------------- QKV GEMM + fused RoPE
// BK=64 (R21/R22-measured win for this kernel: 1536 blocks -> ~5-6/CU TLP),
// XCD swizzle (T1), LDS chunk XOR-swizzle (bank-conflict-free, R18->R19).
__global__ __launch_bounds__(256) void k_gemm_qkv(
        const short* __restrict__ A, const short* __restrict__ Bt,
        const float4* __restrict__ ropetab,
        short* __restrict__ qr, short* __restrict__ kr, short* __restrict__ vt) {
    __shared__ short Asm[128 * 64];
    __shared__ short Bsm[128 * 64];
    int wgid = blockIdx.x;
    int orig = (wgid & 7) * 192 + (wgid >> 3);   // bijective: 1536 = 8*192
    int bx = orig % 12, by = orig / 12;
    int tid = threadIdx.x, wv = tid >> 6, ln = tid & 63;
    int wr = wv >> 1, wc = wv & 1, lr = ln & 15, lg = ln >> 4;
    const short* Ab = A + (size_t)by * 128 * 512;
    const short* Bb = Bt + (size_t)bx * 128 * 512;
    f32x4 acc[4][4] = {};
    int lrow = ln >> 3, lch = ln & 7;
    int schx = (lch ^ (lrow & 7)) * 8;           // swizzled source col (shorts)
    for (int kt = 0; kt < 8; kt++) {
        int kb = kt * 64;
#pragma unroll
        for (int g = 0; g < 4; g++) {
            int row = wv * 32 + g * 8 + lrow;
            gload16(Ab + (size_t)row * 512 + kb + schx, (void*)(Asm + (wv * 32 + g * 8) * 64));
            gload16(Bb + (size_t)row * 512 + kb + schx, (void*)(Bsm + (wv * 32 + g * 8) * 64));
        }
        __syncthreads();
        bf16x8 af[2][4], bfr[2][4];
#pragma unroll
        for (int kk = 0; kk < 2; kk++) {
#pragma unroll
            for (int m = 0; m < 4; m++) {
                int R = wr * 64 + m * 16 + lr;
                af[kk][m] = *(const bf16x8*)(Asm + R * 64 + ((lg + kk * 4) ^ (R & 7)) * 8);
            }
#pragma unroll
            for (int f = 0; f < 4; f++) {
                int R = wc * 64 + f * 16 + lr;
                bfr[kk][f] = *(const bf16x8*)(Bsm + R * 64 + ((lg + kk * 4) ^ (R & 7)) * 8);
            }
        }
#pragma unroll
        for (int kk = 0; kk < 2; kk++)
#pragma unroll
            for (int m = 0; m < 4; m++)
#pragma unroll
                for (int f = 0; f < 4; f++)
                    acc[m][f] = MFMA16(af[kk][m], bfr[kk][f], acc[m][f]);
        __syncthreads();
    }
    int mbase = by * 128;
    int sec = bx >> 2;
    int h = (2 * bx + wc) & 7;
    if (sec < 2) {
        short* dst0 = (sec == 0) ? qr : kr;
#pragma unroll
        for (int m = 0; m < 4; m++) {
            int gmb = mbase + wr * 64 + m * 16 + lg * 4;
#pragma unroll
            for (int r = 0; r < 4; r++) {
                int gm = gmb + r; int b = gm >> 10, n = gm & 1023;
                short* rowp = dst0 + (((size_t)b * NH + h) * N_ + n) * HD;
                const float4* tr = ropetab + n * 32;
#pragma unroll
                for (int f2 = 0; f2 < 2; f2++) {
                    int d_lo = f2 * 16 + lr;
                    float4 t = tr[d_lo];
                    float a = acc[m][f2][r], bb2 = acc[m][f2 + 2][r];
                    rowp[d_lo]      = f2bf_hw(a * t.x - bb2 * t.y);
                    rowp[d_lo + 32] = f2bf_hw(bb2 * t.z + a * t.w);
                }
            }
        }
    } else {
#pragma unroll
        for (int m = 0; m < 4; m++) {
            int gmb = mbase + wr * 64 + m * 16 + lg * 4;
            int b = gmb >> 10, n0 = gmb & 1023;
#pragma unroll
            for (int f = 0; f < 4; f++) {
                int d = f * 16 + lr;
                uint2 val;
                val.x = packcvt(acc[m][f][0], acc[m][f][1]);
                val.y = packcvt(acc[m][f][2], acc[m][f][3]);
                *(uint2*)(vt + (((size_t)b * NH + h) * HD + d) * N_ + n0) = val;
            }
        }
    }
}

// ---------------------------------------------------------------- flash attention v12 (final, depth 4)
// Pipeline depth 4 (Ks[4]/Vs[4], 64 KB LDS; measured best: depth 3 -6.6us,
// 3->4 -1.9us, 4->5 neutral). Grid (bh=128, qt=4): 128 == 0 mod 8 -> all 4
// qt-blocks of a bh on one XCD. 8-wave blocks, 2 q-tiles each. Counted-vmcnt
// (T4), setprio around MFMA (T5, ~-5us), fixed-shift exp2 softmax, permlane
// P-redistribution (T12), XOR-swizzled K/V staging (T2 via m173 pattern).
__global__ __launch_bounds__(512) void k_flash12(
        const short* __restrict__ qr, const short* __restrict__ kr, const short* __restrict__ vt,
        short* __restrict__ attn_out) {
    __shared__ short Ks[4][4096];        // [k=64][d=64] chunk-swizzled
    __shared__ short Vs[4][4096];        // [d=64][k=64] chunk-swizzled
    int bh = blockIdx.x, b = bh >> 3, h = bh & 7;
    int qt = blockIdx.y;
    int tid = threadIdx.x, wv = tid >> 6, ln = tid & 63;
    int lr = ln & 15, lg = ln >> 4;
    int qhalf = wv >> 2, w4 = wv & 3;
    const short* Qb = qr + ((size_t)bh * N_ + qt * 256 + qhalf * 128 + w4 * 32) * HD;
    const short* Kb = kr + (size_t)bh * N_ * HD;
    const short* Vb = vt + (size_t)bh * HD * N_;

    // Q as B-operand fragments, pre-scaled by 0.125*log2(e): S lands in log2 domain
    const float QSCALE = 0.125f * 1.44269504f;
    bf16x8 qf[2][2];
#pragma unroll
    for (int qg = 0; qg < 2; qg++)
#pragma unroll
        for (int hf = 0; hf < 2; hf++) {
            bf16x8 raw = *(const bf16x8*)(Qb + (qg * 16 + lr) * 64 + hf * 32 + lg * 8);
            bf16x8 sc;
#pragma unroll
            for (int j = 0; j < 8; j++) sc[j] = f2bf_hw(bf2f(raw[j]) * QSCALE);
            qf[qg][hf] = sc;
        }

    int srow = ln >> 3, cpos = ln & 7;
    int rloc = wv * 8 + srow;            // 0..63: this wave's K-row / V-row
    int csrc = cpos ^ (srow & 7);

    float l_part[2] = {0.f, 0.f};
    f32x4 ao[2][4] = {};

    // drain Q vector-loads so vmcnt counts only staging gloads from here on
    asm volatile("s_waitcnt vmcnt(0)" ::: "memory");
    __builtin_amdgcn_sched_barrier(0);

    // stage tiles 0,1,2 (2 gloads/wave each)
#pragma unroll
    for (int t0 = 0; t0 < 3; t0++) {
        gload16(Kb + ((size_t)(t0 * 64 + rloc)) * 64 + csrc * 8,
                (void*)&Ks[t0][rloc * 64]);
        gload16(Vb + ((size_t)rloc) * 1024 + t0 * 64 + csrc * 8,
                (void*)&Vs[t0][rloc * 64]);
    }
    asm volatile("s_waitcnt vmcnt(4)" ::: "memory");   // tile 0 complete
    __builtin_amdgcn_s_barrier();
    __builtin_amdgcn_sched_barrier(0);

    for (int kt = 0; kt < 16; kt++) {
        int cur = kt & 3;
        if (kt < 13) {
            int nxt = (kt + 3) & 3, ktn = kt + 3;
            gload16(Kb + ((size_t)(ktn * 64 + rloc)) * 64 + csrc * 8,
                    (void*)&Ks[nxt][rloc * 64]);
            gload16(Vb + ((size_t)rloc) * 1024 + ktn * 64 + csrc * 8,
                    (void*)&Vs[nxt][rloc * 64]);
        }

        // QK^T (swapped): sT[qg][f][r] = S^T[k = f*16+lg*4+r][q = qg*16+lr] (log2 domain)
        f32x4 sT[2][4];
        __builtin_amdgcn_s_setprio(1);
#pragma unroll
        for (int f = 0; f < 4; f++) {
            int r = f * 16 + lr;
            const short* kp = &Ks[cur][r * 64];
            bf16x8 ka  = *(const bf16x8*)(kp + ((lg ^ (r & 7)) * 8));
            bf16x8 kb2 = *(const bf16x8*)(kp + (((4 + lg) ^ (r & 7)) * 8));
#pragma unroll
            for (int qg = 0; qg < 2; qg++) {
                f32x4 s = {};
                s = MFMA16(ka, qf[qg][0], s);
                s = MFMA16(kb2, qf[qg][1], s);
                sT[qg][f] = s;
            }
        }
        __builtin_amdgcn_s_setprio(0);

        // fixed-shift softmax: p = exp2(s) directly; l accumulated per-lane
        union U4 { unsigned u[4]; bf16x8 v; };
        U4 pb[2][2];
#pragma unroll
        for (int qg = 0; qg < 2; qg++) {
            float rsum = 0.f;
            unsigned pk[4][2];
#pragma unroll
            for (int f = 0; f < 4; f++) {
                float p0 = fexp2(sT[qg][f][0]);
                float p1 = fexp2(sT[qg][f][1]);
                float p2 = fexp2(sT[qg][f][2]);
                float p3 = fexp2(sT[qg][f][3]);
                rsum += (p0 + p1) + (p2 + p3);
                pk[f][0] = packcvt(p0, p1);
                pk[f][1] = packcvt(p2, p3);
            }
            l_part[qg] += rsum;

            // redistribute pk -> pb (B-operand fragments) in-register
#pragma unroll
            for (int kb = 0; kb < 2; kb++) {
                unsigned a = pk[2 * kb][0], c = pk[2 * kb + 1][0];
                plswap32(a, c); plswap16(a, c);
                pb[qg][kb].u[0] = a; pb[qg][kb].u[2] = c;
                unsigned bb = pk[2 * kb][1], d = pk[2 * kb + 1][1];
                plswap32(bb, d); plswap16(bb, d);
                pb[qg][kb].u[1] = bb; pb[qg][kb].u[3] = d;
            }
        }

        // PV: O^T += V^T-frag x P^T-frag
        __builtin_amdgcn_s_setprio(1);
#pragma unroll
        for (int dt = 0; dt < 4; dt++) {
            int rr = dt * 16 + lr;
            const short* vp = &Vs[cur][rr * 64];
            bf16x8 va0 = *(const bf16x8*)(vp + ((lg ^ (rr & 7)) * 8));
            bf16x8 va1 = *(const bf16x8*)(vp + (((4 + lg) ^ (rr & 7)) * 8));
#pragma unroll
            for (int qg = 0; qg < 2; qg++) {
                ao[qg][dt] = MFMA16(va0, pb[qg][0].v, ao[qg][dt]);
                ao[qg][dt] = MFMA16(va1, pb[qg][1].v, ao[qg][dt]);
            }
        }
        __builtin_amdgcn_s_setprio(0);

        if (kt < 15) {
            if (kt < 13)      asm volatile("s_waitcnt vmcnt(4)" ::: "memory");
            else if (kt == 13) asm volatile("s_waitcnt vmcnt(2)" ::: "memory");
            else               asm volatile("s_waitcnt vmcnt(0)" ::: "memory");
            __builtin_amdgcn_s_barrier();
            __builtin_amdgcn_sched_barrier(0);
        }
    }

    // epilogue: one cross-lane l reduction, normalize, store 8B chunks
#pragma unroll
    for (int qg = 0; qg < 2; qg++) {
        float inv = 1.0f / redsum_lg(l_part[qg]);
        int qglob = qt * 256 + qhalf * 128 + w4 * 32 + qg * 16 + lr;
        size_t ob = ((size_t)b * N_ + qglob) * 512 + h * 64 + lg * 4;
#pragma unroll
        for (int dt = 0; dt < 4; dt++) {
            uint2 val;
            val.x = packcvt(ao[qg][dt][0] * inv, ao[qg][dt][1] * inv);
            val.y = packcvt(ao[qg][dt][2] * inv, ao[qg][dt][3] * inv);
            *(uint2*)(attn_out + ob + dt * 16) = val;
        }
    }
}

// ---------------------------------------------------------------- out proj (transposed: M=channels)
// Final config: BK=32, 128x128 tiles, grid (128,4), XOR swizzle (both BK=64
// and 128x64 split regressed -> latency-structural floor for this kernel).
__global__ __launch_bounds__(256) void k_gemm_out(
        const short* __restrict__ A, const short* __restrict__ Bt,
        const float* __restrict__ x, const float* __restrict__ obias, float* __restrict__ out) {
    __shared__ short Asm[128 * 32];
    __shared__ short Bsm[128 * 32];
    int tid = threadIdx.x, wv = tid >> 6, ln = tid & 63;
    int wr = wv >> 1, wc = wv & 1, lr = ln & 15, lg = ln >> 4;
    const short* Ab = A + (size_t)blockIdx.y * 128 * 512;
    const short* Bb = Bt + (size_t)blockIdx.x * 128 * 512;
    f32x4 acc[4][4] = {};
    int srow = ln >> 2, sch = ln & 3;
    int sx = sch ^ ((srow >> 1) & 3);
    for (int kb = 0; kb < 512; kb += 32) {
        int r0 = wv * 32;
        const short* ga = Ab + (size_t)(r0 + srow) * 512 + kb + sx * 8;
        gload16(ga, (void*)(Asm + r0 * 32));
        gload16(ga + 16 * 512, (void*)(Asm + (r0 + 16) * 32));
        const short* gbp = Bb + (size_t)(r0 + srow) * 512 + kb + sx * 8;
        gload16(gbp, (void*)(Bsm + r0 * 32));
        gload16(gbp + 16 * 512, (void*)(Bsm + (r0 + 16) * 32));
        __syncthreads();
        bf16x8 af[4], bfr[4];
#pragma unroll
        for (int m = 0; m < 4; m++) {
            int R = wr * 64 + m * 16 + lr;
            af[m] = *(const bf16x8*)(Asm + R * 32 + (lg ^ ((R >> 1) & 3)) * 8);
        }
#pragma unroll
        for (int f = 0; f < 4; f++) {
            int R = wc * 64 + f * 16 + lr;
            bfr[f] = *(const bf16x8*)(Bsm + R * 32 + (lg ^ ((R >> 1) & 3)) * 8);
        }
#pragma unroll
        for (int m = 0; m < 4; m++)
#pragma unroll
            for (int f = 0; f < 4; f++)
                acc[m][f] = MFMA16(af[m], bfr[f], acc[m][f]);
        __syncthreads();
    }
    int cb = blockIdx.y * 128 + wr * 64, tb = blockIdx.x * 128 + wc * 64;
#pragma unroll
    for (int m = 0; m < 4; m++) {
#pragma unroll
        for (int f = 0; f < 4; f++) {
            int gt = tb + f * 16 + lr;
            int b = gt >> 10, n = gt & 1023;
#pragma unroll
            for (int r = 0; r < 4; r++) {
                int gc = cb + m * 16 + lg * 4 + r;
                size_t ad = ((size_t)b * C_ + gc) * N_ + n;
                out[ad] = acc[m][f][r] + obias[gc] + x[ad];
            }
        }
    }
}

// ---------------------------------------------------------------- launch
extern "C" void kernel_launch(void* const* d_in, const int* in_sizes, int n_in,
                              void* d_out, int out_size, void* d_ws, size_t ws_size,
                              hipStream_t stream) {
    const float* x     = (const float*)d_in[0];
    const float* temb  = (const float*)d_in[1];
    const float* tm_w1 = (const float*)d_in[2];
    const float* tm_b1 = (const float*)d_in[3];
    const float* tm_w2 = (const float*)d_in[4];
    const float* tm_b2 = (const float*)d_in[5];
    const float* qkv_w = (const float*)d_in[6];
    const float* out_w = (const float*)d_in[7];
    const float* out_b = (const float*)d_in[8];
    float* out = (float*)d_out;

    char* ws = (char*)d_ws;
    short*  qkvwT  = (short*)(ws);                 // 1536*512*2  = 1,572,864
    short*  outwT  = (short*)(ws + 1572864);       //  512*512*2  =   524,288
    float4* ropetab= (float4*)(ws + 2097152);      // 1024*32*16  =   524,288
    float*  gb     = (float*)(ws + 2621440);       // 16*1024*4
    short*  tokens = (short*)(ws + 2686976);       // 16384*512*2 = 16,777,216 (also attn_out)
    short*  qr     = (short*)(ws + 19464192);      // 16,777,216
    short*  kr     = (short*)(ws + 36241408);
    short*  vt     = (short*)(ws + 53018624);      // end ~66.6 MB
    short*  attn   = tokens;                        // tokens dead after k_gemm_qkv
    float*  hbuf   = (float*)(ws + 2686976);       // 16*512*4 = 32 KB, inside tokens
                                                   // region (dead until adacln)

    k_prep1<<<dim3(640), dim3(256), 0, stream>>>(qkv_w, out_w, qkvwT, outwT, ropetab,
                                                 temb, tm_w1, tm_b1, hbuf);
    k_mlp2<<<dim3(32, 16), dim3(256), 0, stream>>>(hbuf, tm_w2, tm_b2, gb);
    k_adacln<<<dim3(16, 16), dim3(256), 0, stream>>>(x, gb, tokens);
    k_gemm_qkv<<<dim3(1536), dim3(256), 0, stream>>>(tokens, qkvwT, ropetab, qr, kr, vt);
    k_flash12<<<dim3(128, 4), dim3(512), 0, stream>>>(qr, kr, vt, attn);
    k_gemm_out<<<dim3(128, 4), dim3(256), 0, stream>>>(outwT, attn, x, out_b, out);
}

// Round 31
// 127.325 us; speedup vs baseline: 1.0285x; 1.0216x over previous
//
#include <hip/hip_runtime.h>
#include <stdint.h>
#include <stddef.h>

// Problem constants
#define B_  16
#define C_  512
#define N_  1024    // H*W = 32*32
#define NH  8
#define HD  64

typedef __attribute__((ext_vector_type(8))) short bf16x8;
typedef __attribute__((ext_vector_type(4))) float f32x4;
typedef __attribute__((ext_vector_type(2))) __bf16 bf16x2t;
typedef __attribute__((ext_vector_type(2))) unsigned uint2v;

__device__ __forceinline__ float bf2f(short s) {
    unsigned u = ((unsigned)(unsigned short)s) << 16;
    return __builtin_bit_cast(float, u);
}
// Compiler-visible f32->bf16 (RNE): lowers to v_cvt_pk_bf16_f32 on gfx950.
__device__ __forceinline__ unsigned packcvt(float lo, float hi) {
    bf16x2t v = { (__bf16)lo, (__bf16)hi };
    return __builtin_bit_cast(unsigned, v);
}
__device__ __forceinline__ short f2bf_hw(float f) {
    __bf16 b = (__bf16)f;
    return __builtin_bit_cast(short, b);
}
// Native 2^x (v_exp_f32 IS exp2; denorm flush-to-zero is fine for softmax tails)
__device__ __forceinline__ float fexp2(float x) {
#if __has_builtin(__builtin_amdgcn_exp2f)
    return __builtin_amdgcn_exp2f(x);
#else
    return exp2f(x);
#endif
}
// Two-register half-swaps (gfx950). swap32: a's lanes32-63 <-> b's lanes0-31.
// swap16: a's odd 16-rows <-> b's even 16-rows.
__device__ __forceinline__ void plswap32(unsigned& a, unsigned& b) {
#if __has_builtin(__builtin_amdgcn_permlane32_swap)
    uint2v r = __builtin_amdgcn_permlane32_swap(a, b, false, false);
    a = r.x; b = r.y;
#else
    unsigned ax = (unsigned)__shfl_xor((int)a, 32, 64), bx = (unsigned)__shfl_xor((int)b, 32, 64);
    bool hi = (threadIdx.x & 32) != 0;
    unsigned na = hi ? bx : a, nb = hi ? b : ax;
    a = na; b = nb;
#endif
}
__device__ __forceinline__ void plswap16(unsigned& a, unsigned& b) {
#if __has_builtin(__builtin_amdgcn_permlane16_swap)
    uint2v r = __builtin_amdgcn_permlane16_swap(a, b, false, false);
    a = r.x; b = r.y;
#else
    unsigned ax = (unsigned)__shfl_xor((int)a, 16, 64), bx = (unsigned)__shfl_xor((int)b, 16, 64);
    bool hi = (threadIdx.x & 16) != 0;
    unsigned na = hi ? bx : a, nb = hi ? b : ax;
    a = na; b = nb;
#endif
}
__device__ __forceinline__ float bcf(unsigned u) { return __builtin_bit_cast(float, u); }
__device__ __forceinline__ unsigned bcu(float f) { return __builtin_bit_cast(unsigned, f); }
// butterfly reduce across lane bits 4,5 (the 4 lane-groups): result valid in all lanes
__device__ __forceinline__ float redsum_lg(float x) {
    unsigned a = bcu(x), b = a; plswap32(a, b);
    float s = bcf(a) + bcf(b);
    a = bcu(s); b = a; plswap16(a, b);
    return bcf(a) + bcf(b);
}

#define MFMA16(a, b, c) __builtin_amdgcn_mfma_f32_16x16x32_bf16((a), (b), (c), 0, 0, 0)

typedef __attribute__((address_space(3))) unsigned int lds_u32;
typedef __attribute__((address_space(1))) unsigned int glb_u32;
// dest = wave-uniform LDS base + lane*16 (m104); global src is per-lane.
__device__ __forceinline__ void gload16(const void* g, void* l) {
    __builtin_amdgcn_global_load_lds((const glb_u32*)g, (lds_u32*)l, 16, 0, 0);
}

// ---------------------------------------------------------------- prep + mlp1 + adacln-stats (merged)
// bid < 192: qkv_w transpose; bid < 256: out_w transpose; bid < 384: rope
// table; bid < 640: mlp1 h = silu(temb@w1+b1); bid >= 640 (256 blocks):
// adacln STATS pass (mean/rstd per pixel -> sbuf). Stats depend only on x,
// so they overlap prep/mlp1 here instead of running serially inside adacln.
// sbuf aliases the qr region: written here, read by k_adacln_apply, and qr
// itself is first written by k_gemm_qkv (strictly later) -> no overlap.
__global__ __launch_bounds__(256) void k_prep1(
        const float* __restrict__ qkv_w, const float* __restrict__ out_w,
        short* __restrict__ qkvwT, short* __restrict__ outwT,
        float4* __restrict__ ropetab,
        const float* __restrict__ temb, const float* __restrict__ w1,
        const float* __restrict__ b1, float* __restrict__ h,
        const float* __restrict__ x, float2* __restrict__ sbuf) {
    int bid = blockIdx.x, tid = threadIdx.x;
    __shared__ float ts[64][65];
    __shared__ float ps[8][32];
    __shared__ float4 sr[16][16], sqa[16][16];
    if (bid < 256) {
        const float* src; short* dst; int J, jt, kt;
        if (bid < 192) { src = qkv_w; dst = qkvwT; J = 1536; jt = (bid % 24) * 64; kt = (bid / 24) * 64; }
        else { int b2 = bid - 192; src = out_w; dst = outwT; J = 512; jt = (b2 & 7) * 64; kt = (b2 >> 3) * 64; }
        int r = tid >> 4, c4 = (tid & 15) * 4;
        for (int rr = 0; rr < 64; rr += 16) {
            float4 v = *(const float4*)(src + (size_t)(kt + rr + r) * J + jt + c4);
            ts[c4 + 0][rr + r] = v.x;
            ts[c4 + 1][rr + r] = v.y;
            ts[c4 + 2][rr + r] = v.z;
            ts[c4 + 3][rr + r] = v.w;
        }
        __syncthreads();
        int jr = tid >> 2, kc = (tid & 3) * 16;
        unsigned w[8];
#pragma unroll
        for (int i = 0; i < 8; i++) w[i] = packcvt(ts[jr][kc + 2 * i], ts[jr][kc + 2 * i + 1]);
        short* dp = dst + (size_t)(jt + jr) * 512 + kt + kc;
        *(uint4*)(dp)     = make_uint4(w[0], w[1], w[2], w[3]);
        *(uint4*)(dp + 8) = make_uint4(w[4], w[5], w[6], w[7]);
    } else if (bid < 384) {
        int idx = (bid - 256) * 256 + tid;       // 32768 entries
        int n = idx >> 5, dq = idx & 31, i = dq & 15;
        float w = powf(100.0f, -(float)i * (1.0f / 16.0f));
        float y = (float)(n >> 5), xx = (float)(n & 31);
        ropetab[idx] = make_float4(cosf(y * w), sinf(y * w), cosf(xx * w), sinf(xx * w));
    } else if (bid < 640) {
        // mlp1: rem = bid-384; jt = rem%16, b = rem/16
        int rem = bid - 384;
        int jt = rem & 15, b = rem >> 4;
        int jl = tid & 31, j = jt * 32 + jl, ks = tid >> 5;
        float* tl = &ts[0][0];                    // reuse LDS (512 floats)
        tl[tid] = temb[b * 512 + tid];
        tl[tid + 256] = temb[b * 512 + tid + 256];
        __syncthreads();
        float acc = 0.f;
        const float* wp = w1 + (size_t)(ks * 64) * 512 + j;
#pragma unroll 8
        for (int kk = 0; kk < 64; kk++) acc += tl[ks * 64 + kk] * wp[(size_t)kk * 512];
        ps[ks][jl] = acc;
        __syncthreads();
        if (tid < 32) {
            float s = ((ps[0][tid] + ps[1][tid]) + (ps[2][tid] + ps[3][tid]))
                    + ((ps[4][tid] + ps[5][tid]) + (ps[6][tid] + ps[7][tid]));
            s += b1[jt * 32 + tid];
            h[b * 512 + jt * 32 + tid] = s / (1.0f + __expf(-s));
        }
    } else {
        // adacln stats: rem = bid-640; n0 = (rem&15)*64, b = rem>>4
        int rem = bid - 640;
        int n0 = (rem & 15) * 64, b = rem >> 4;
        const float* xb = x + (size_t)b * C_ * N_;
        int q = tid & 15, s = tid >> 4;
        float4 sum = make_float4(0.f, 0.f, 0.f, 0.f);
        float4 sq  = make_float4(0.f, 0.f, 0.f, 0.f);
        const float* xp = xb + (size_t)(s * 32) * N_ + n0 + q * 4;
#pragma unroll 8
        for (int ci = 0; ci < 32; ci++) {
            float4 v = *(const float4*)(xp + (size_t)ci * N_);
            sum.x += v.x; sum.y += v.y; sum.z += v.z; sum.w += v.w;
            sq.x += v.x * v.x; sq.y += v.y * v.y; sq.z += v.z * v.z; sq.w += v.w * v.w;
        }
        sr[s][q] = sum; sqa[s][q] = sq;
        __syncthreads();
        if (tid < 64) {
            int qq = tid >> 2, j = tid & 3;
            float s1 = 0.f, s2 = 0.f;
#pragma unroll
            for (int ss = 0; ss < 16; ss++) {
                float4 a = sr[ss][qq], c = sqa[ss][qq];
                s1 += (&a.x)[j];
                s2 += (&c.x)[j];
            }
            float mu = s1 * (1.0f / 512.0f);
            float var = s2 * (1.0f / 512.0f) - mu * mu;
            sbuf[b * 1024 + n0 + tid] = make_float2(mu, rsqrtf(var + 1e-6f));
        }
    }
}

__global__ __launch_bounds__(256) void k_mlp2(
        const float* __restrict__ h, const float* __restrict__ w2, const float* __restrict__ b2,
        float* __restrict__ gbout) {
    int b = blockIdx.y, jt = blockIdx.x, tid = threadIdx.x;
    int jl = tid & 31, j = jt * 32 + jl, ks = tid >> 5;
    __shared__ float hl[512];
    __shared__ float ps[8][32];
    hl[tid] = h[b * 512 + tid];
    hl[tid + 256] = h[b * 512 + tid + 256];
    __syncthreads();
    float acc = 0.f;
    const float* wp = w2 + (size_t)(ks * 64) * 1024 + j;
#pragma unroll 8
    for (int kk = 0; kk < 64; kk++) acc += hl[ks * 64 + kk] * wp[(size_t)kk * 1024];
    ps[ks][jl] = acc;
    __syncthreads();
    if (tid < 32) {
        float s = ((ps[0][tid] + ps[1][tid]) + (ps[2][tid] + ps[3][tid]))
                + ((ps[4][tid] + ps[5][tid]) + (ps[6][tid] + ps[7][tid]));
        gbout[b * 1024 + jt * 32 + tid] = s + b2[jt * 32 + tid];
    }
}

// ---------------------------------------------------------------- AdaCLN apply -> tokens bf16 (B,N,C)
// Stats precomputed in k_prep1 (sbuf). x re-read here is L3-resident
// (33.5 MB, touched two dispatches earlier, nothing evicts it). The first
// __syncthreads in the ct loop orders the stats load before use.
__global__ __launch_bounds__(256) void k_adacln(
        const float* __restrict__ x, const float* __restrict__ gb,
        const float2* __restrict__ sbuf, short* __restrict__ tokens) {
    int b = blockIdx.y, n0 = blockIdx.x * 64;
    int tid = threadIdx.x;
    const float* xb = x + (size_t)b * C_ * N_;
    __shared__ float mean_s[64], rstd_s[64];
    __shared__ float xs[64][65];
    if (tid < 64) {
        float2 ms = sbuf[b * 1024 + n0 + tid];
        mean_s[tid] = ms.x;
        rstd_s[tid] = ms.y;
    }
    const float* gam = gb + b * 1024;
    const float* bet = gam + 512;
    int ch = tid & 7;
    for (int ct = 0; ct < 8; ct++) {
        __syncthreads();
#pragma unroll
        for (int itr = 0; itr < 4; itr++) {
            int cl = itr * 16 + (tid >> 4), q = tid & 15;
            float4 v = *(const float4*)(xb + (size_t)(ct * 64 + cl) * N_ + n0 + q * 4);
            xs[cl][q * 4 + 0] = v.x;
            xs[cl][q * 4 + 1] = v.y;
            xs[cl][q * 4 + 2] = v.z;
            xs[cl][q * 4 + 3] = v.w;
        }
        __syncthreads();
#pragma unroll
        for (int pp = 0; pp < 2; pp++) {
            int p = pp * 32 + (tid >> 3);
            float mu = mean_s[p], rt = rstd_s[p];
            float v[8];
#pragma unroll
            for (int j = 0; j < 8; j++) {
                int c = ct * 64 + ch * 8 + j;
                v[j] = (xs[ch * 8 + j][p] - mu) * rt * (1.0f + gam[c]) + bet[c];
            }
            uint4 ov = make_uint4(packcvt(v[0], v[1]), packcvt(v[2], v[3]),
                                  packcvt(v[4], v[5]), packcvt(v[6], v[7]));
            *(uint4*)(tokens + ((size_t)(b * N_ + n0 + p)) * C_ + ct * 64 + ch * 8) = ov;
        }
    }
}

// ---------------------------------------------------------------- QKV GEMM + fused RoPE
// BK=64 (R21/R22-measured win for this kernel: 1536 blocks -> ~5-6/CU TLP),
// XCD swizzle (T1), LDS chunk XOR-swizzle (bank-conflict-free, R18->R19).
__global__ __launch_bounds__(256) void k_gemm_qkv(
        const short* __restrict__ A, const short* __restrict__ Bt,
        const float4* __restrict__ ropetab,
        short* __restrict__ qr, short* __restrict__ kr, short* __restrict__ vt) {
    __shared__ short Asm[128 * 64];
    __shared__ short Bsm[128 * 64];
    int wgid = blockIdx.x;
    int orig = (wgid & 7) * 192 + (wgid >> 3);   // bijective: 1536 = 8*192
    int bx = orig % 12, by = orig / 12;
    int tid = threadIdx.x, wv = tid >> 6, ln = tid & 63;
    int wr = wv >> 1, wc = wv & 1, lr = ln & 15, lg = ln >> 4;
    const short* Ab = A + (size_t)by * 128 * 512;
    const short* Bb = Bt + (size_t)bx * 128 * 512;
    f32x4 acc[4][4] = {};
    int lrow = ln >> 3, lch = ln & 7;
    int schx = (lch ^ (lrow & 7)) * 8;           // swizzled source col (shorts)
    for (int kt = 0; kt < 8; kt++) {
        int kb = kt * 64;
#pragma unroll
        for (int g = 0; g < 4; g++) {
            int row = wv * 32 + g * 8 + lrow;
            gload16(Ab + (size_t)row * 512 + kb + schx, (void*)(Asm + (wv * 32 + g * 8) * 64));
            gload16(Bb + (size_t)row * 512 + kb + schx, (void*)(Bsm + (wv * 32 + g * 8) * 64));
        }
        __syncthreads();
        bf16x8 af[2][4], bfr[2][4];
#pragma unroll
        for (int kk = 0; kk < 2; kk++) {
#pragma unroll
            for (int m = 0; m < 4; m++) {
                int R = wr * 64 + m * 16 + lr;
                af[kk][m] = *(const bf16x8*)(Asm + R * 64 + ((lg + kk * 4) ^ (R & 7)) * 8);
            }
#pragma unroll
            for (int f = 0; f < 4; f++) {
                int R = wc * 64 + f * 16 + lr;
                bfr[kk][f] = *(const bf16x8*)(Bsm + R * 64 + ((lg + kk * 4) ^ (R & 7)) * 8);
            }
        }
#pragma unroll
        for (int kk = 0; kk < 2; kk++)
#pragma unroll
            for (int m = 0; m < 4; m++)
#pragma unroll
                for (int f = 0; f < 4; f++)
                    acc[m][f] = MFMA16(af[kk][m], bfr[kk][f], acc[m][f]);
        __syncthreads();
    }
    int mbase = by * 128;
    int sec = bx >> 2;
    int h = (2 * bx + wc) & 7;
    if (sec < 2) {
        short* dst0 = (sec == 0) ? qr : kr;
#pragma unroll
        for (int m = 0; m < 4; m++) {
            int gmb = mbase + wr * 64 + m * 16 + lg * 4;
#pragma unroll
            for (int r = 0; r < 4; r++) {
                int gm = gmb + r; int b = gm >> 10, n = gm & 1023;
                short* rowp = dst0 + (((size_t)b * NH + h) * N_ + n) * HD;
                const float4* tr = ropetab + n * 32;
#pragma unroll
                for (int f2 = 0; f2 < 2; f2++) {
                    int d_lo = f2 * 16 + lr;
                    float4 t = tr[d_lo];
                    float a = acc[m][f2][r], bb2 = acc[m][f2 + 2][r];
                    rowp[d_lo]      = f2bf_hw(a * t.x - bb2 * t.y);
                    rowp[d_lo + 32] = f2bf_hw(bb2 * t.z + a * t.w);
                }
            }
        }
    } else {
#pragma unroll
        for (int m = 0; m < 4; m++) {
            int gmb = mbase + wr * 64 + m * 16 + lg * 4;
            int b = gmb >> 10, n0 = gmb & 1023;
#pragma unroll
            for (int f = 0; f < 4; f++) {
                int d = f * 16 + lr;
                uint2 val;
                val.x = packcvt(acc[m][f][0], acc[m][f][1]);
                val.y = packcvt(acc[m][f][2], acc[m][f][3]);
                *(uint2*)(vt + (((size_t)b * NH + h) * HD + d) * N_ + n0) = val;
            }
        }
    }
}

// ---------------------------------------------------------------- flash attention v12 (final, depth 4)
// Pipeline depth 4 (Ks[4]/Vs[4], 64 KB LDS; measured best: depth 3 -6.6us,
// 3->4 -1.9us, 4->5 neutral). Grid (bh=128, qt=4): 128 == 0 mod 8 -> all 4
// qt-blocks of a bh on one XCD. 8-wave blocks, 2 q-tiles each. Counted-vmcnt
// (T4), setprio around MFMA (T5, ~-5us), fixed-shift exp2 softmax, permlane
// P-redistribution (T12), XOR-swizzled K/V staging (T2 via m173 pattern).
__global__ __launch_bounds__(512) void k_flash12(
        const short* __restrict__ qr, const short* __restrict__ kr, const short* __restrict__ vt,
        short* __restrict__ attn_out) {
    __shared__ short Ks[4][4096];        // [k=64][d=64] chunk-swizzled
    __shared__ short Vs[4][4096];        // [d=64][k=64] chunk-swizzled
    int bh = blockIdx.x, b = bh >> 3, h = bh & 7;
    int qt = blockIdx.y;
    int tid = threadIdx.x, wv = tid >> 6, ln = tid & 63;
    int lr = ln & 15, lg = ln >> 4;
    int qhalf = wv >> 2, w4 = wv & 3;
    const short* Qb = qr + ((size_t)bh * N_ + qt * 256 + qhalf * 128 + w4 * 32) * HD;
    const short* Kb = kr + (size_t)bh * N_ * HD;
    const short* Vb = vt + (size_t)bh * HD * N_;

    // Q as B-operand fragments, pre-scaled by 0.125*log2(e): S lands in log2 domain
    const float QSCALE = 0.125f * 1.44269504f;
    bf16x8 qf[2][2];
#pragma unroll
    for (int qg = 0; qg < 2; qg++)
#pragma unroll
        for (int hf = 0; hf < 2; hf++) {
            bf16x8 raw = *(const bf16x8*)(Qb + (qg * 16 + lr) * 64 + hf * 32 + lg * 8);
            bf16x8 sc;
#pragma unroll
            for (int j = 0; j < 8; j++) sc[j] = f2bf_hw(bf2f(raw[j]) * QSCALE);
            qf[qg][hf] = sc;
        }

    int srow = ln >> 3, cpos = ln & 7;
    int rloc = wv * 8 + srow;            // 0..63: this wave's K-row / V-row
    int csrc = cpos ^ (srow & 7);

    float l_part[2] = {0.f, 0.f};
    f32x4 ao[2][4] = {};

    // drain Q vector-loads so vmcnt counts only staging gloads from here on
    asm volatile("s_waitcnt vmcnt(0)" ::: "memory");
    __builtin_amdgcn_sched_barrier(0);

    // stage tiles 0,1,2 (2 gloads/wave each)
#pragma unroll
    for (int t0 = 0; t0 < 3; t0++) {
        gload16(Kb + ((size_t)(t0 * 64 + rloc)) * 64 + csrc * 8,
                (void*)&Ks[t0][rloc * 64]);
        gload16(Vb + ((size_t)rloc) * 1024 + t0 * 64 + csrc * 8,
                (void*)&Vs[t0][rloc * 64]);
    }
    asm volatile("s_waitcnt vmcnt(4)" ::: "memory");   // tile 0 complete
    __builtin_amdgcn_s_barrier();
    __builtin_amdgcn_sched_barrier(0);

    for (int kt = 0; kt < 16; kt++) {
        int cur = kt & 3;
        if (kt < 13) {
            int nxt = (kt + 3) & 3, ktn = kt + 3;
            gload16(Kb + ((size_t)(ktn * 64 + rloc)) * 64 + csrc * 8,
                    (void*)&Ks[nxt][rloc * 64]);
            gload16(Vb + ((size_t)rloc) * 1024 + ktn * 64 + csrc * 8,
                    (void*)&Vs[nxt][rloc * 64]);
        }

        // QK^T (swapped): sT[qg][f][r] = S^T[k = f*16+lg*4+r][q = qg*16+lr] (log2 domain)
        f32x4 sT[2][4];
        __builtin_amdgcn_s_setprio(1);
#pragma unroll
        for (int f = 0; f < 4; f++) {
            int r = f * 16 + lr;
            const short* kp = &Ks[cur][r * 64];
            bf16x8 ka  = *(const bf16x8*)(kp + ((lg ^ (r & 7)) * 8));
            bf16x8 kb2 = *(const bf16x8*)(kp + (((4 + lg) ^ (r & 7)) * 8));
#pragma unroll
            for (int qg = 0; qg < 2; qg++) {
                f32x4 s = {};
                s = MFMA16(ka, qf[qg][0], s);
                s = MFMA16(kb2, qf[qg][1], s);
                sT[qg][f] = s;
            }
        }
        __builtin_amdgcn_s_setprio(0);

        // fixed-shift softmax: p = exp2(s) directly; l accumulated per-lane
        union U4 { unsigned u[4]; bf16x8 v; };
        U4 pb[2][2];
#pragma unroll
        for (int qg = 0; qg < 2; qg++) {
            float rsum = 0.f;
            unsigned pk[4][2];
#pragma unroll
            for (int f = 0; f < 4; f++) {
                float p0 = fexp2(sT[qg][f][0]);
                float p1 = fexp2(sT[qg][f][1]);
                float p2 = fexp2(sT[qg][f][2]);
                float p3 = fexp2(sT[qg][f][3]);
                rsum += (p0 + p1) + (p2 + p3);
                pk[f][0] = packcvt(p0, p1);
                pk[f][1] = packcvt(p2, p3);
            }
            l_part[qg] += rsum;

            // redistribute pk -> pb (B-operand fragments) in-register
#pragma unroll
            for (int kb = 0; kb < 2; kb++) {
                unsigned a = pk[2 * kb][0], c = pk[2 * kb + 1][0];
                plswap32(a, c); plswap16(a, c);
                pb[qg][kb].u[0] = a; pb[qg][kb].u[2] = c;
                unsigned bb = pk[2 * kb][1], d = pk[2 * kb + 1][1];
                plswap32(bb, d); plswap16(bb, d);
                pb[qg][kb].u[1] = bb; pb[qg][kb].u[3] = d;
            }
        }

        // PV: O^T += V^T-frag x P^T-frag
        __builtin_amdgcn_s_setprio(1);
#pragma unroll
        for (int dt = 0; dt < 4; dt++) {
            int rr = dt * 16 + lr;
            const short* vp = &Vs[cur][rr * 64];
            bf16x8 va0 = *(const bf16x8*)(vp + ((lg ^ (rr & 7)) * 8));
            bf16x8 va1 = *(const bf16x8*)(vp + (((4 + lg) ^ (rr & 7)) * 8));
#pragma unroll
            for (int qg = 0; qg < 2; qg++) {
                ao[qg][dt] = MFMA16(va0, pb[qg][0].v, ao[qg][dt]);
                ao[qg][dt] = MFMA16(va1, pb[qg][1].v, ao[qg][dt]);
            }
        }
        __builtin_amdgcn_s_setprio(0);

        if (kt < 15) {
            if (kt < 13)      asm volatile("s_waitcnt vmcnt(4)" ::: "memory");
            else if (kt == 13) asm volatile("s_waitcnt vmcnt(2)" ::: "memory");
            else               asm volatile("s_waitcnt vmcnt(0)" ::: "memory");
            __builtin_amdgcn_s_barrier();
            __builtin_amdgcn_sched_barrier(0);
        }
    }

    // epilogue: one cross-lane l reduction, normalize, store 8B chunks
#pragma unroll
    for (int qg = 0; qg < 2; qg++) {
        float inv = 1.0f / redsum_lg(l_part[qg]);
        int qglob = qt * 256 + qhalf * 128 + w4 * 32 + qg * 16 + lr;
        size_t ob = ((size_t)b * N_ + qglob) * 512 + h * 64 + lg * 4;
#pragma unroll
        for (int dt = 0; dt < 4; dt++) {
            uint2 val;
            val.x = packcvt(ao[qg][dt][0] * inv, ao[qg][dt][1] * inv);
            val.y = packcvt(ao[qg][dt][2] * inv, ao[qg][dt][3] * inv);
            *(uint2*)(attn_out + ob + dt * 16) = val;
        }
    }
}

// ---------------------------------------------------------------- out proj (transposed: M=channels)
// Final config: BK=32, 128x128 tiles, grid (128,4), XOR swizzle (both BK=64
// and 128x64 split regressed -> latency-structural floor for this kernel).
__global__ __launch_bounds__(256) void k_gemm_out(
        const short* __restrict__ A, const short* __restrict__ Bt,
        const float* __restrict__ x, const float* __restrict__ obias, float* __restrict__ out) {
    __shared__ short Asm[128 * 32];
    __shared__ short Bsm[128 * 32];
    int tid = threadIdx.x, wv = tid >> 6, ln = tid & 63;
    int wr = wv >> 1, wc = wv & 1, lr = ln & 15, lg = ln >> 4;
    const short* Ab = A + (size_t)blockIdx.y * 128 * 512;
    const short* Bb = Bt + (size_t)blockIdx.x * 128 * 512;
    f32x4 acc[4][4] = {};
    int srow = ln >> 2, sch = ln & 3;
    int sx = sch ^ ((srow >> 1) & 3);
    for (int kb = 0; kb < 512; kb += 32) {
        int r0 = wv * 32;
        const short* ga = Ab + (size_t)(r0 + srow) * 512 + kb + sx * 8;
        gload16(ga, (void*)(Asm + r0 * 32));
        gload16(ga + 16 * 512, (void*)(Asm + (r0 + 16) * 32));
        const short* gbp = Bb + (size_t)(r0 + srow) * 512 + kb + sx * 8;
        gload16(gbp, (void*)(Bsm + r0 * 32));
        gload16(gbp + 16 * 512, (void*)(Bsm + (r0 + 16) * 32));
        __syncthreads();
        bf16x8 af[4], bfr[4];
#pragma unroll
        for (int m = 0; m < 4; m++) {
            int R = wr * 64 + m * 16 + lr;
            af[m] = *(const bf16x8*)(Asm + R * 32 + (lg ^ ((R >> 1) & 3)) * 8);
        }
#pragma unroll
        for (int f = 0; f < 4; f++) {
            int R = wc * 64 + f * 16 + lr;
            bfr[f] = *(const bf16x8*)(Bsm + R * 32 + (lg ^ ((R >> 1) & 3)) * 8);
        }
#pragma unroll
        for (int m = 0; m < 4; m++)
#pragma unroll
            for (int f = 0; f < 4; f++)
                acc[m][f] = MFMA16(af[m], bfr[f], acc[m][f]);
        __syncthreads();
    }
    int cb = blockIdx.y * 128 + wr * 64, tb = blockIdx.x * 128 + wc * 64;
#pragma unroll
    for (int m = 0; m < 4; m++) {
#pragma unroll
        for (int f = 0; f < 4; f++) {
            int gt = tb + f * 16 + lr;
            int b = gt >> 10, n = gt & 1023;
#pragma unroll
            for (int r = 0; r < 4; r++) {
                int gc = cb + m * 16 + lg * 4 + r;
                size_t ad = ((size_t)b * C_ + gc) * N_ + n;
                out[ad] = acc[m][f][r] + obias[gc] + x[ad];
            }
        }
    }
}

// ---------------------------------------------------------------- launch
extern "C" void kernel_launch(void* const* d_in, const int* in_sizes, int n_in,
                              void* d_out, int out_size, void* d_ws, size_t ws_size,
                              hipStream_t stream) {
    const float* x     = (const float*)d_in[0];
    const float* temb  = (const float*)d_in[1];
    const float* tm_w1 = (const float*)d_in[2];
    const float* tm_b1 = (const float*)d_in[3];
    const float* tm_w2 = (const float*)d_in[4];
    const float* tm_b2 = (const float*)d_in[5];
    const float* qkv_w = (const float*)d_in[6];
    const float* out_w = (const float*)d_in[7];
    const float* out_b = (const float*)d_in[8];
    float* out = (float*)d_out;

    char* ws = (char*)d_ws;
    short*  qkvwT  = (short*)(ws);                 // 1536*512*2  = 1,572,864
    short*  outwT  = (short*)(ws + 1572864);       //  512*512*2  =   524,288
    float4* ropetab= (float4*)(ws + 2097152);      // 1024*32*16  =   524,288
    float*  gb     = (float*)(ws + 2621440);       // 16*1024*4
    short*  tokens = (short*)(ws + 2686976);       // 16384*512*2 = 16,777,216 (also attn_out)
    short*  qr     = (short*)(ws + 19464192);      // 16,777,216
    short*  kr     = (short*)(ws + 36241408);
    short*  vt     = (short*)(ws + 53018624);      // end ~66.6 MB
    short*  attn   = tokens;                        // tokens dead after k_gemm_qkv
    float*  hbuf   = (float*)(ws + 2686976);       // 16*512*4 = 32 KB, inside tokens
                                                   // region (dead until adacln)
    float2* sbuf   = (float2*)(ws + 19464192);     // 16*1024*8 = 131 KB, aliases qr:
                                                   // written by prep1, read by adacln,
                                                   // qr first written in gemm_qkv (later)

    k_prep1<<<dim3(896), dim3(256), 0, stream>>>(qkv_w, out_w, qkvwT, outwT, ropetab,
                                                 temb, tm_w1, tm_b1, hbuf, x, sbuf);
    k_mlp2<<<dim3(32, 16), dim3(256), 0, stream>>>(hbuf, tm_w2, tm_b2, gb);
    k_adacln<<<dim3(16, 16), dim3(256), 0, stream>>>(x, gb, sbuf, tokens);
    k_gemm_qkv<<<dim3(1536), dim3(256), 0, stream>>>(tokens, qkvwT, ropetab, qr, kr, vt);
    k_flash12<<<dim3(128, 4), dim3(512), 0, stream>>>(qr, kr, vt, attn);
    k_gemm_out<<<dim3(128, 4), dim3(256), 0, stream>>>(outwT, attn, x, out_b, out);
}